// Round 3
// baseline (270.630 us; speedup 1.0000x reference)
//
#include <hip/hip_runtime.h>

typedef unsigned short u16;
typedef __bf16 bf16x8 __attribute__((ext_vector_type(8)));
typedef float f32x4 __attribute__((ext_vector_type(4)));

#define LOG2E 1.44269504088896f

__device__ __forceinline__ u16 f2bf(float f) {
  unsigned int u = __builtin_bit_cast(unsigned int, f);
  u += 0x7fffu + ((u >> 16) & 1u);
  return (u16)(u >> 16);
}

// ---------------------------------------------------------------- cast x -> bf16
__global__ __launch_bounds__(256) void cast_x(const float* __restrict__ in,
                                              u16* __restrict__ out) {
  long i = ((long)blockIdx.x * 256 + threadIdx.x) * 8;
  float4 a = *(const float4*)(in + i);
  float4 b = *(const float4*)(in + i + 4);
  union { u16 u[8]; int4 v; } pk;
  pk.u[0] = f2bf(a.x); pk.u[1] = f2bf(a.y); pk.u[2] = f2bf(a.z); pk.u[3] = f2bf(a.w);
  pk.u[4] = f2bf(b.x); pk.u[5] = f2bf(b.y); pk.u[6] = f2bf(b.z); pk.u[7] = f2bf(b.w);
  *(int4*)(out + i) = pk.v;
}

// ------------------------------------------- transpose+cast weights: [K][N] f32 -> [N][K] bf16
__global__ __launch_bounds__(256) void transpose_cast(const float* __restrict__ in,
                                                      u16* __restrict__ out,
                                                      int K, int N) {
  __shared__ float tile[32][33];
  const int n0 = blockIdx.x * 32, k0 = blockIdx.y * 32;
  const int tx = threadIdx.x, ty = threadIdx.y;  // (32,8)
#pragma unroll
  for (int i = 0; i < 4; ++i)
    tile[ty + i * 8][tx] = in[(long)(k0 + ty + i * 8) * N + n0 + tx];
  __syncthreads();
#pragma unroll
  for (int i = 0; i < 4; ++i)
    out[(long)(n0 + ty + i * 8) * K + k0 + tx] = f2bf(tile[tx][ty + i * 8]);
}

// ------------------------------------------- transpose V: qkv v-part -> vt[bh][d][t]
__global__ __launch_bounds__(256) void transpose_v(const u16* __restrict__ qkv,
                                                   u16* __restrict__ vt) {
  __shared__ __align__(16) u16 tile[64][72];  // stride 144 B = 9*16 -> int4 stays aligned
  const int bid = blockIdx.x;
  const int tt = bid & 31;
  const int bh = bid >> 5;
  const int b = bh >> 4, hh = bh & 15;
  const long t0 = (long)tt * 64;
  const u16* src = qkv + ((long)b * 2048 + t0) * 3072 + 2048 + hh * 64;
#pragma unroll
  for (int i = 0; i < 2; ++i) {
    int e = (int)threadIdx.x + i * 256;  // 0..511
    int t = e >> 3, c = (e & 7) * 8;
    *(int4*)&tile[t][c] = *(const int4*)(src + (long)t * 3072 + c);
  }
  __syncthreads();
  u16* dst = vt + (long)bh * 64 * 2048 + t0;
#pragma unroll
  for (int i = 0; i < 2; ++i) {
    int e = (int)threadIdx.x + i * 256;
    int d = e >> 3, tc = (e & 7) * 8;
    union { u16 u[8]; int4 v; } pk;
#pragma unroll
    for (int j = 0; j < 8; ++j) pk.u[j] = tile[tc + j][d];
    *(int4*)(dst + (long)d * 2048 + tc) = pk.v;
  }
}

// ------------------------------------------- GEMM: C[M][N] = A[M][K] * Bt[N][K]^T + bias
// Correctness-first variant: register-staged LDS (no global_load_lds), padded
// stride 40 u16 (80 B = 5*16 -> b128 aligned, near-conflict-free frag reads).
template <typename OutT>
__global__ __launch_bounds__(256) void gemm_bt(const u16* __restrict__ A,
                                               const u16* __restrict__ Bt,
                                               const float* __restrict__ bias,
                                               OutT* __restrict__ C,
                                               int M, int N, int K) {
  __shared__ __align__(16) u16 lA[128 * 40];
  __shared__ __align__(16) u16 lB[128 * 40];
  const int tid = (int)threadIdx.x;
  const int ln = tid & 63;
  const int w = tid >> 6;
  const int wr = w >> 1, wc = w & 1;
  const int lr = ln & 15, lg = ln >> 4;
  const long mBase = (long)blockIdx.y * 128;
  const long nBase = (long)blockIdx.x * 128;

  f32x4 acc[4][4] = {};

  const int r0 = ln >> 2;        // 0..15
  const int c0 = (ln & 3) * 8;   // 0,8,16,24
  const int row0 = w * 16 + r0;        // rows 0..63 across waves
  const int row1 = (4 + w) * 16 + r0;  // rows 64..127

  for (int k0 = 0; k0 < K; k0 += 32) {
    const int4 va0 = *(const int4*)(A + (mBase + row0) * K + k0 + c0);
    const int4 va1 = *(const int4*)(A + (mBase + row1) * K + k0 + c0);
    const int4 vb0 = *(const int4*)(Bt + (nBase + row0) * K + k0 + c0);
    const int4 vb1 = *(const int4*)(Bt + (nBase + row1) * K + k0 + c0);
    __syncthreads();  // prior iteration's fragment reads done
    *(int4*)&lA[row0 * 40 + c0] = va0;
    *(int4*)&lA[row1 * 40 + c0] = va1;
    *(int4*)&lB[row0 * 40 + c0] = vb0;
    *(int4*)&lB[row1 * 40 + c0] = vb1;
    __syncthreads();  // writes visible to all waves
    bf16x8 af[4], bfv[4];
#pragma unroll
    for (int mi = 0; mi < 4; ++mi)
      af[mi] = *(const bf16x8*)&lA[(wr * 64 + mi * 16 + lr) * 40 + lg * 8];
#pragma unroll
    for (int ni = 0; ni < 4; ++ni)
      bfv[ni] = *(const bf16x8*)&lB[(wc * 64 + ni * 16 + lr) * 40 + lg * 8];
#pragma unroll
    for (int mi = 0; mi < 4; ++mi)
#pragma unroll
      for (int ni = 0; ni < 4; ++ni)
        acc[mi][ni] = __builtin_amdgcn_mfma_f32_16x16x32_bf16(af[mi], bfv[ni],
                                                              acc[mi][ni], 0, 0, 0);
  }

#pragma unroll
  for (int ni = 0; ni < 4; ++ni) {
    const long col = nBase + wc * 64 + ni * 16 + lr;
    const float bv = bias[col];
#pragma unroll
    for (int mi = 0; mi < 4; ++mi) {
      const long row = mBase + wr * 64 + mi * 16 + lg * 4;
#pragma unroll
      for (int j = 0; j < 4; ++j) {
        float v = acc[mi][ni][j] + bv;
        if constexpr (sizeof(OutT) == 2) {
          C[(row + j) * N + col] = (OutT)f2bf(v);
        } else {
          C[(row + j) * N + col] = v;
        }
      }
    }
  }
}

// ------------------------------------------- flash attention (correctness-first)
// grid: 512 blocks = 32 (b,h) * 16 q-tiles(128). 4 independent waves, 32 q-rows
// each. K and Vt fragments loaded DIRECTLY from global (L2-resident); only the
// per-wave P C-frag->A-frag relayout goes through LDS (linear, fenced).
__global__ __launch_bounds__(256) void attn_fwd(const u16* __restrict__ qkv,
                                                const u16* __restrict__ vt,
                                                u16* __restrict__ outp) {
  __shared__ __align__(16) u16 lP[4][32 * 64];
  const int tid = (int)threadIdx.x;
  const int ln = tid & 63;
  const int w = tid >> 6;
  const int bid = (int)blockIdx.x;
  const int qt = bid & 15;
  const int bh = bid >> 4;
  const int b = bh >> 4;
  const int hh = bh & 15;
  const int lr = ln & 15;  // fragment row/col lane
  const int lg = ln >> 4;  // k-group 0..3
  u16* lPw = &lP[w][0];

  // Q fragments (A-operand): row = q (lr), k = d
  const u16* Qp = qkv + ((long)(b * 2048 + qt * 128 + w * 32)) * 3072 + hh * 64;
  bf16x8 qf[2][2];
#pragma unroll
  for (int mi = 0; mi < 2; ++mi)
#pragma unroll
    for (int ks = 0; ks < 2; ++ks)
      qf[mi][ks] = *(const bf16x8*)(Qp + (long)(mi * 16 + lr) * 3072 + ks * 32 + lg * 8);

  f32x4 o[2][4] = {};
  float mrow[2][4], lsum[2][4];
#pragma unroll
  for (int mi = 0; mi < 2; ++mi)
#pragma unroll
    for (int j = 0; j < 4; ++j) { mrow[mi][j] = -1e30f; lsum[mi][j] = 0.f; }

  const u16* Kbase = qkv + ((long)b * 2048) * 3072 + 1024 + hh * 64;
  const u16* Vbase = vt + (long)bh * 64 * 2048;

  for (int kt = 0; kt < 32; ++kt) {
    const int kv0 = kt * 64;

    // ---- QK^T: S[32 q][64 kv] per wave; K B-frags direct from global
    bf16x8 kf[4][2];
#pragma unroll
    for (int nf = 0; nf < 4; ++nf)
#pragma unroll
      for (int ks = 0; ks < 2; ++ks)
        kf[nf][ks] = *(const bf16x8*)(Kbase + (long)(kv0 + nf * 16 + lr) * 3072 +
                                      ks * 32 + lg * 8);
    f32x4 sc[2][4] = {};
#pragma unroll
    for (int mi = 0; mi < 2; ++mi)
#pragma unroll
      for (int nf = 0; nf < 4; ++nf)
#pragma unroll
        for (int ks = 0; ks < 2; ++ks)
          sc[mi][nf] = __builtin_amdgcn_mfma_f32_16x16x32_bf16(qf[mi][ks], kf[nf][ks],
                                                               sc[mi][nf], 0, 0, 0);

    // ---- online softmax (row = mi*16+lg*4+j lives across the 16 lr-lanes)
#pragma unroll
    for (int mi = 0; mi < 2; ++mi) {
#pragma unroll
      for (int j = 0; j < 4; ++j) {
        float s0 = sc[mi][0][j] * 0.125f, s1 = sc[mi][1][j] * 0.125f;
        float s2 = sc[mi][2][j] * 0.125f, s3 = sc[mi][3][j] * 0.125f;
        float mx = fmaxf(fmaxf(s0, s1), fmaxf(s2, s3));
        mx = fmaxf(mx, __shfl_xor(mx, 1));
        mx = fmaxf(mx, __shfl_xor(mx, 2));
        mx = fmaxf(mx, __shfl_xor(mx, 4));
        mx = fmaxf(mx, __shfl_xor(mx, 8));
        const float mnew = fmaxf(mrow[mi][j], mx);
        const float sf = exp2f((mrow[mi][j] - mnew) * LOG2E);
        mrow[mi][j] = mnew;
        const float p0 = exp2f((s0 - mnew) * LOG2E);
        const float p1 = exp2f((s1 - mnew) * LOG2E);
        const float p2 = exp2f((s2 - mnew) * LOG2E);
        const float p3 = exp2f((s3 - mnew) * LOG2E);
        float rs = p0 + p1 + p2 + p3;
        rs += __shfl_xor(rs, 1);
        rs += __shfl_xor(rs, 2);
        rs += __shfl_xor(rs, 4);
        rs += __shfl_xor(rs, 8);
        lsum[mi][j] = lsum[mi][j] * sf + rs;
        o[mi][0][j] *= sf; o[mi][1][j] *= sf; o[mi][2][j] *= sf; o[mi][3][j] *= sf;
        // write P (bf16) to per-wave LDS, linear [32 q][64 kv]
        const int prow = mi * 16 + lg * 4 + j;
        lPw[prow * 64 + 0 * 16 + lr] = f2bf(p0);
        lPw[prow * 64 + 1 * 16 + lr] = f2bf(p1);
        lPw[prow * 64 + 2 * 16 + lr] = f2bf(p2);
        lPw[prow * 64 + 3 * 16 + lr] = f2bf(p3);
      }
    }
    asm volatile("s_waitcnt lgkmcnt(0)" ::: "memory");
    __builtin_amdgcn_sched_barrier(0);

    // ---- PV: O += P[32 q][64 kv] * V[64 kv][64 d]; Vt B-frags direct from global
    bf16x8 vf[4][2], pf[2][2];
#pragma unroll
    for (int nf = 0; nf < 4; ++nf)
#pragma unroll
      for (int ks = 0; ks < 2; ++ks)
        vf[nf][ks] = *(const bf16x8*)(Vbase + (long)(nf * 16 + lr) * 2048 +
                                      kv0 + ks * 32 + lg * 8);
#pragma unroll
    for (int mi = 0; mi < 2; ++mi)
#pragma unroll
      for (int ks = 0; ks < 2; ++ks)
        pf[mi][ks] = *(const bf16x8*)&lPw[(mi * 16 + lr) * 64 + ks * 32 + lg * 8];
#pragma unroll
    for (int mi = 0; mi < 2; ++mi)
#pragma unroll
      for (int nf = 0; nf < 4; ++nf)
#pragma unroll
        for (int ks = 0; ks < 2; ++ks)
          o[mi][nf] = __builtin_amdgcn_mfma_f32_16x16x32_bf16(pf[mi][ks], vf[nf][ks],
                                                              o[mi][nf], 0, 0, 0);
    // fence: this tile's P-reads must complete before next tile's P-writes
    asm volatile("s_waitcnt lgkmcnt(0)" ::: "memory");
    __builtin_amdgcn_sched_barrier(0);
  }

  // epilogue: divide by row sum, write bf16 out[b,t, h*64+d]
#pragma unroll
  for (int mi = 0; mi < 2; ++mi)
#pragma unroll
    for (int j = 0; j < 4; ++j) {
      const float inv = 1.0f / lsum[mi][j];
      const int qrow = qt * 128 + w * 32 + mi * 16 + lg * 4 + j;
      u16* orow = outp + ((long)(b * 2048 + qrow)) * 1024 + hh * 64;
#pragma unroll
      for (int nf = 0; nf < 4; ++nf)
        orow[nf * 16 + lr] = f2bf(o[mi][nf][j] * inv);
    }
}

// ----------------------------------------------------------------------------
extern "C" void kernel_launch(void* const* d_in, const int* in_sizes, int n_in,
                              void* d_out, int out_size, void* d_ws, size_t ws_size,
                              hipStream_t stream) {
  (void)in_sizes; (void)n_in; (void)out_size;
  const float* x = (const float*)d_in[0];
  const float* b_attn = (const float*)d_in[2];
  const float* b_qkv = (const float*)d_in[4];
  const float* b_proj = (const float*)d_in[6];

  char* ws = (char*)d_ws;
  const size_t MB = 1024 * 1024;
  u16* xb   = (u16*)(ws + 0 * MB);    // 8 MB  [4096][1024]
  u16* hbuf = (u16*)(ws + 8 * MB);    // 8 MB  [4096][1024]
  u16* qkvb = (u16*)(ws + 16 * MB);   // 24 MB [4096][3072]
  u16* vtb  = (u16*)(ws + 40 * MB);   // 8 MB  [32][64][2048]
  u16* aout = (u16*)(ws + 48 * MB);   // 8 MB  [4096][1024]
  u16* wTa  = (u16*)(ws + 56 * MB);   // 2 MB  [1024][1024]
  u16* wTq  = (u16*)(ws + 58 * MB);   // 6 MB  [3072][1024]
  u16* wTp  = (u16*)(ws + 64 * MB);   // 2 MB  [1024][1024]
  if (ws_size < 66 * MB) return;      // would corrupt -> fail loudly instead

  // prep
  cast_x<<<2048, 256, 0, stream>>>(x, xb);
  dim3 tcb(32, 8);
  transpose_cast<<<dim3(32, 32), tcb, 0, stream>>>((const float*)d_in[1], wTa, 1024, 1024);
  transpose_cast<<<dim3(96, 32), tcb, 0, stream>>>((const float*)d_in[3], wTq, 1024, 3072);
  transpose_cast<<<dim3(32, 32), tcb, 0, stream>>>((const float*)d_in[5], wTp, 1024, 1024);

  // h = x @ w_attn + b_attn
  gemm_bt<u16><<<dim3(8, 32), 256, 0, stream>>>(xb, wTa, b_attn, hbuf, 4096, 1024, 1024);
  // qkv = h @ w_qkv + b_qkv
  gemm_bt<u16><<<dim3(24, 32), 256, 0, stream>>>(hbuf, wTq, b_qkv, qkvb, 4096, 3072, 1024);
  // vt[bh][d][t]
  transpose_v<<<1024, 256, 0, stream>>>(qkvb, vtb);
  // attention
  attn_fwd<<<512, 256, 0, stream>>>(qkvb, vtb, aout);
  // out = attn_out @ w_proj + b_proj  (FLOAT32 output — the round-3 experiment)
  gemm_bt<float><<<dim3(8, 32), 256, 0, stream>>>(aout, wTp, b_proj, (float*)d_out,
                                                  4096, 1024, 1024);
}

// Round 4
// 252.962 us; speedup vs baseline: 1.0698x; 1.0698x over previous
//
#include <hip/hip_runtime.h>

typedef unsigned short u16;
typedef __bf16 bf16x8 __attribute__((ext_vector_type(8)));
typedef float f32x4 __attribute__((ext_vector_type(4)));

typedef const __attribute__((address_space(1))) void* gcp_t;
typedef __attribute__((address_space(3))) void* lp_t;
#define GLDS16(g, l) __builtin_amdgcn_global_load_lds((gcp_t)(g), (lp_t)(l), 16, 0, 0)

__device__ __forceinline__ u16 f2bf(float f) {
  unsigned int u = __builtin_bit_cast(unsigned int, f);
  u += 0x7fffu + ((u >> 16) & 1u);
  return (u16)(u >> 16);
}

// ---------------------------------------------------------------- cast x -> bf16
__global__ __launch_bounds__(256) void cast_x(const float* __restrict__ in,
                                              u16* __restrict__ out) {
  long i = ((long)blockIdx.x * 256 + threadIdx.x) * 8;
  float4 a = *(const float4*)(in + i);
  float4 b = *(const float4*)(in + i + 4);
  union { u16 u[8]; int4 v; } pk;
  pk.u[0] = f2bf(a.x); pk.u[1] = f2bf(a.y); pk.u[2] = f2bf(a.z); pk.u[3] = f2bf(a.w);
  pk.u[4] = f2bf(b.x); pk.u[5] = f2bf(b.y); pk.u[6] = f2bf(b.z); pk.u[7] = f2bf(b.w);
  *(int4*)(out + i) = pk.v;
}

// ------------------------------------------- transpose+cast weights: [K][N] f32 -> [N][K] bf16
__global__ __launch_bounds__(256) void transpose_cast(const float* __restrict__ in,
                                                      u16* __restrict__ out,
                                                      int K, int N) {
  __shared__ float tile[32][33];
  const int n0 = blockIdx.x * 32, k0 = blockIdx.y * 32;
  const int tx = threadIdx.x, ty = threadIdx.y;  // (32,8)
#pragma unroll
  for (int i = 0; i < 4; ++i)
    tile[ty + i * 8][tx] = in[(long)(k0 + ty + i * 8) * N + n0 + tx];
  __syncthreads();
#pragma unroll
  for (int i = 0; i < 4; ++i)
    out[(long)(n0 + ty + i * 8) * K + k0 + tx] = f2bf(tile[tx][ty + i * 8]);
}

// ------------------------------------------- transpose V: qkv v-part -> vt[bh][d][t]
__global__ __launch_bounds__(256) void transpose_v(const u16* __restrict__ qkv,
                                                   u16* __restrict__ vt) {
  __shared__ __align__(16) u16 tile[64][72];
  const int bid = blockIdx.x;
  const int tt = bid & 31;
  const int bh = bid >> 5;
  const int b = bh >> 4, hh = bh & 15;
  const long t0 = (long)tt * 64;
  const u16* src = qkv + ((long)b * 2048 + t0) * 3072 + 2048 + hh * 64;
#pragma unroll
  for (int i = 0; i < 2; ++i) {
    int e = (int)threadIdx.x + i * 256;  // 0..511
    int t = e >> 3, c = (e & 7) * 8;
    *(int4*)&tile[t][c] = *(const int4*)(src + (long)t * 3072 + c);
  }
  __syncthreads();
  u16* dst = vt + (long)bh * 64 * 2048 + t0;
#pragma unroll
  for (int i = 0; i < 2; ++i) {
    int e = (int)threadIdx.x + i * 256;
    int d = e >> 3, tc = (e & 7) * 8;
    union { u16 u[8]; int4 v; } pk;
#pragma unroll
    for (int j = 0; j < 8; ++j) pk.u[j] = tile[tc + j][d];
    *(int4*)(dst + (long)d * 2048 + tc) = pk.v;
  }
}

// ------------------------------------------- GEMM: C[M][N] = A[M][K] * Bt[N][K]^T + bias
// m97 structure (verified bit-identical in R0/R1): 128x128 tile, BK=32, 4 waves,
// global_load_lds width-16 staging.
template <typename OutT>
__global__ __launch_bounds__(256) void gemm_bt(const u16* __restrict__ A,
                                               const u16* __restrict__ Bt,
                                               const float* __restrict__ bias,
                                               OutT* __restrict__ C,
                                               int M, int N, int K) {
  __shared__ __align__(16) u16 lA[128 * 32];
  __shared__ __align__(16) u16 lB[128 * 32];
  const int tid = (int)threadIdx.x;
  const int ln = tid & 63;
  const int w = tid >> 6;
  const int wr = w >> 1, wc = w & 1;
  const int lr = ln & 15, lg = ln >> 4;
  const long mBase = (long)blockIdx.y * 128;
  const long nBase = (long)blockIdx.x * 128;

  f32x4 acc[4][4] = {};

  const int r0 = ln >> 2;        // 0..15 (row within 16-row staging chunk)
  const int c0 = (ln & 3) * 8;   // element offset within row

  for (int k0 = 0; k0 < K; k0 += 32) {
#pragma unroll
    for (int i = 0; i < 2; ++i) {
      const int br = (i * 4 + w) * 16;
      GLDS16(A + (mBase + br + r0) * K + k0 + c0, lA + br * 32);
      GLDS16(Bt + (nBase + br + r0) * K + k0 + c0, lB + br * 32);
    }
    __syncthreads();
    bf16x8 af[4], bfv[4];
#pragma unroll
    for (int mi = 0; mi < 4; ++mi)
      af[mi] = *(const bf16x8*)&lA[(wr * 64 + mi * 16 + lr) * 32 + lg * 8];
#pragma unroll
    for (int ni = 0; ni < 4; ++ni)
      bfv[ni] = *(const bf16x8*)&lB[(wc * 64 + ni * 16 + lr) * 32 + lg * 8];
#pragma unroll
    for (int mi = 0; mi < 4; ++mi)
#pragma unroll
      for (int ni = 0; ni < 4; ++ni)
        acc[mi][ni] = __builtin_amdgcn_mfma_f32_16x16x32_bf16(af[mi], bfv[ni],
                                                              acc[mi][ni], 0, 0, 0);
    __syncthreads();
  }

#pragma unroll
  for (int ni = 0; ni < 4; ++ni) {
    const long col = nBase + wc * 64 + ni * 16 + lr;
    const float bv = bias[col];
#pragma unroll
    for (int mi = 0; mi < 4; ++mi) {
      const long row = mBase + wr * 64 + mi * 16 + lg * 4;
#pragma unroll
      for (int j = 0; j < 4; ++j) {
        float v = acc[mi][ni][j] + bv;
        if constexpr (sizeof(OutT) == 2) {
          C[(row + j) * N + col] = (OutT)f2bf(v);
        } else {
          C[(row + j) * N + col] = v;
        }
      }
    }
  }
}

// ------------------------------------------- flash attention v3
// grid: 1024 blocks = 32 (b,h) * 32 q-tiles(64). 4 waves, 16 q-rows each.
// K/V tiles (64 kv x 64 d / 64 d x 64 kv) LDS-staged via GLDS16 with
// pre-swizzled source + XOR reads (R0-verified). Softmax in log2 domain,
// defer-max, per-lane deferred lsum. P via padded per-wave LDS (stride 72).
__global__ __launch_bounds__(256) void attn_fwd(const u16* __restrict__ qkv,
                                                const u16* __restrict__ vt,
                                                u16* __restrict__ outp) {
  __shared__ __align__(16) u16 lK[64 * 64];
  __shared__ __align__(16) u16 lV[64 * 64];
  __shared__ __align__(16) u16 lP[4][16 * 72];
  const int tid = (int)threadIdx.x;
  const int ln = tid & 63;
  const int w = tid >> 6;
  const int bid = (int)blockIdx.x;
  const int qt = bid & 31;
  const int bh = bid >> 5;
  const int b = bh >> 4;
  const int hh = bh & 15;
  const int lr = ln & 15;
  const int lg = ln >> 4;
  u16* lPw = &lP[w][0];

  const float SCALE = 0.125f * 1.44269504088896f;  // 1/sqrt(64) * log2(e)

  // Q fragments: 16 rows per wave
  const u16* Qp = qkv + ((long)(b * 2048 + qt * 64 + w * 16)) * 3072 + hh * 64;
  bf16x8 qf[2];
#pragma unroll
  for (int ks = 0; ks < 2; ++ks)
    qf[ks] = *(const bf16x8*)(Qp + (long)lr * 3072 + ks * 32 + lg * 8);

  f32x4 o[4] = {};
  float mrow[4], lsum[4];
#pragma unroll
  for (int j = 0; j < 4; ++j) { mrow[j] = -1e30f; lsum[j] = 0.f; }

  const u16* Kbase = qkv + ((long)b * 2048) * 3072 + 1024 + hh * 64;
  const u16* Vbase = vt + (long)bh * 64 * 2048;

  const int sr = ln >> 3;                // 0..7 row within 8-row staging chunk
  const int scm = ln & 7;                // chunk col 0..7

  for (int kt = 0; kt < 32; ++kt) {
    const int kv0 = kt * 64;
    // ---- stage K and Vt tiles (source pre-swizzled; LDS dest linear)
#pragma unroll
    for (int i = 0; i < 2; ++i) {
      const int br = (i * 4 + w) * 8;
      const int r = br + sr;
      const int cs = scm ^ (r & 7);
      GLDS16(Kbase + (long)(kv0 + r) * 3072 + cs * 8, lK + br * 64);
      GLDS16(Vbase + (long)r * 2048 + kv0 + cs * 8, lV + br * 64);
    }
    __syncthreads();

    // ---- QK^T: S[16 q][64 kv]
    f32x4 sc[4] = {};
#pragma unroll
    for (int nf = 0; nf < 4; ++nf) {
#pragma unroll
      for (int ks = 0; ks < 2; ++ks) {
        const int row = nf * 16 + lr;
        int off = (row * 64 + ks * 32 + lg * 8) * 2;
        off ^= (row & 7) << 4;
        const bf16x8 kf = *(const bf16x8*)((const char*)lK + off);
        sc[nf] = __builtin_amdgcn_mfma_f32_16x16x32_bf16(qf[ks], kf, sc[nf], 0, 0, 0);
      }
    }

    // ---- online softmax, log2 domain, defer-max, deferred lsum
#pragma unroll
    for (int j = 0; j < 4; ++j) {
      float s0 = sc[0][j] * SCALE, s1 = sc[1][j] * SCALE;
      float s2 = sc[2][j] * SCALE, s3 = sc[3][j] * SCALE;
      float mx = fmaxf(fmaxf(s0, s1), fmaxf(s2, s3));
      mx = fmaxf(mx, __shfl_xor(mx, 1));
      mx = fmaxf(mx, __shfl_xor(mx, 2));
      mx = fmaxf(mx, __shfl_xor(mx, 4));
      mx = fmaxf(mx, __shfl_xor(mx, 8));
      if (!__all(mx <= mrow[j] + 8.0f)) {
        const float mnew = fmaxf(mrow[j], mx);
        const float sf = exp2f(mrow[j] - mnew);
        mrow[j] = mnew;
        lsum[j] *= sf;
        o[0][j] *= sf; o[1][j] *= sf; o[2][j] *= sf; o[3][j] *= sf;
      }
      const float m = mrow[j];
      const float p0 = exp2f(s0 - m);
      const float p1 = exp2f(s1 - m);
      const float p2 = exp2f(s2 - m);
      const float p3 = exp2f(s3 - m);
      lsum[j] += (p0 + p1) + (p2 + p3);   // per-lane partial; reduced in epilogue
      const int prow = lg * 4 + j;
      lPw[prow * 72 + 0 * 16 + lr] = f2bf(p0);
      lPw[prow * 72 + 1 * 16 + lr] = f2bf(p1);
      lPw[prow * 72 + 2 * 16 + lr] = f2bf(p2);
      lPw[prow * 72 + 3 * 16 + lr] = f2bf(p3);
    }
    asm volatile("s_waitcnt lgkmcnt(0)" ::: "memory");
    __builtin_amdgcn_sched_barrier(0);

    // ---- PV: O += P[16 q][64 kv] * Vt[64 d][64 kv]^T
    bf16x8 pf[2];
#pragma unroll
    for (int ks = 0; ks < 2; ++ks)
      pf[ks] = *(const bf16x8*)&lPw[lr * 72 + ks * 32 + lg * 8];
#pragma unroll
    for (int nf = 0; nf < 4; ++nf) {
#pragma unroll
      for (int ks = 0; ks < 2; ++ks) {
        const int row = nf * 16 + lr;
        int off = (row * 64 + ks * 32 + lg * 8) * 2;
        off ^= (row & 7) << 4;
        const bf16x8 vf = *(const bf16x8*)((const char*)lV + off);
        o[nf] = __builtin_amdgcn_mfma_f32_16x16x32_bf16(pf[ks], vf, o[nf], 0, 0, 0);
      }
    }
    __syncthreads();
  }

  // ---- epilogue: reduce lsum across the 16-lane row group, normalize, store
#pragma unroll
  for (int j = 0; j < 4; ++j) {
    float rs = lsum[j];
    rs += __shfl_xor(rs, 1);
    rs += __shfl_xor(rs, 2);
    rs += __shfl_xor(rs, 4);
    rs += __shfl_xor(rs, 8);
    const float inv = 1.0f / rs;
    const int qrow = qt * 64 + w * 16 + lg * 4 + j;
    u16* orow = outp + ((long)(b * 2048 + qrow)) * 1024 + hh * 64;
#pragma unroll
    for (int nf = 0; nf < 4; ++nf)
      orow[nf * 16 + lr] = f2bf(o[nf][j] * inv);
  }
}

// ----------------------------------------------------------------------------
extern "C" void kernel_launch(void* const* d_in, const int* in_sizes, int n_in,
                              void* d_out, int out_size, void* d_ws, size_t ws_size,
                              hipStream_t stream) {
  (void)in_sizes; (void)n_in; (void)out_size;
  const float* x = (const float*)d_in[0];
  const float* b_attn = (const float*)d_in[2];
  const float* b_qkv = (const float*)d_in[4];
  const float* b_proj = (const float*)d_in[6];

  char* ws = (char*)d_ws;
  const size_t MB = 1024 * 1024;
  u16* xb   = (u16*)(ws + 0 * MB);    // 8 MB  [4096][1024]
  u16* hbuf = (u16*)(ws + 8 * MB);    // 8 MB  [4096][1024]
  u16* qkvb = (u16*)(ws + 16 * MB);   // 24 MB [4096][3072]
  u16* vtb  = (u16*)(ws + 40 * MB);   // 8 MB  [32][64][2048]
  u16* aout = (u16*)(ws + 48 * MB);   // 8 MB  [4096][1024]
  u16* wTa  = (u16*)(ws + 56 * MB);   // 2 MB  [1024][1024]
  u16* wTq  = (u16*)(ws + 58 * MB);   // 6 MB  [3072][1024]
  u16* wTp  = (u16*)(ws + 64 * MB);   // 2 MB  [1024][1024]
  if (ws_size < 66 * MB) return;

  cast_x<<<2048, 256, 0, stream>>>(x, xb);
  dim3 tcb(32, 8);
  transpose_cast<<<dim3(32, 32), tcb, 0, stream>>>((const float*)d_in[1], wTa, 1024, 1024);
  transpose_cast<<<dim3(96, 32), tcb, 0, stream>>>((const float*)d_in[3], wTq, 1024, 3072);
  transpose_cast<<<dim3(32, 32), tcb, 0, stream>>>((const float*)d_in[5], wTp, 1024, 1024);

  gemm_bt<u16><<<dim3(8, 32), 256, 0, stream>>>(xb, wTa, b_attn, hbuf, 4096, 1024, 1024);
  gemm_bt<u16><<<dim3(24, 32), 256, 0, stream>>>(hbuf, wTq, b_qkv, qkvb, 4096, 3072, 1024);
  transpose_v<<<1024, 256, 0, stream>>>(qkvb, vtb);
  attn_fwd<<<1024, 256, 0, stream>>>(qkvb, vtb, aout);
  gemm_bt<float><<<dim3(8, 32), 256, 0, stream>>>(aout, wTp, b_proj, (float*)d_out,
                                                  4096, 1024, 1024);
}

// Round 5
// 240.981 us; speedup vs baseline: 1.1230x; 1.0497x over previous
//
#include <hip/hip_runtime.h>

typedef unsigned short u16;
typedef __bf16 bf16x8 __attribute__((ext_vector_type(8)));
typedef float f32x4 __attribute__((ext_vector_type(4)));

typedef const __attribute__((address_space(1))) void* gcp_t;
typedef __attribute__((address_space(3))) void* lp_t;
#define GLDS16(g, l) __builtin_amdgcn_global_load_lds((gcp_t)(g), (lp_t)(l), 16, 0, 0)

__device__ __forceinline__ u16 f2bf(float f) {
  unsigned int u = __builtin_bit_cast(unsigned int, f);
  u += 0x7fffu + ((u >> 16) & 1u);
  return (u16)(u >> 16);
}
__device__ __forceinline__ u16 bfc(float f) {          // via HW cvt (RNE)
  return __builtin_bit_cast(u16, (__bf16)f);
}

// ---------------------------------------------------------------- cast x -> bf16
__global__ __launch_bounds__(256) void cast_x(const float* __restrict__ in,
                                              u16* __restrict__ out) {
  long i = ((long)blockIdx.x * 256 + threadIdx.x) * 8;
  float4 a = *(const float4*)(in + i);
  float4 b = *(const float4*)(in + i + 4);
  union { u16 u[8]; int4 v; } pk;
  pk.u[0] = f2bf(a.x); pk.u[1] = f2bf(a.y); pk.u[2] = f2bf(a.z); pk.u[3] = f2bf(a.w);
  pk.u[4] = f2bf(b.x); pk.u[5] = f2bf(b.y); pk.u[6] = f2bf(b.z); pk.u[7] = f2bf(b.w);
  *(int4*)(out + i) = pk.v;
}

// ------------------------------------------- transpose+cast weights: [K][N] f32 -> [N][K] bf16
__global__ __launch_bounds__(256) void transpose_cast(const float* __restrict__ in,
                                                      u16* __restrict__ out,
                                                      int K, int N) {
  __shared__ float tile[32][33];
  const int n0 = blockIdx.x * 32, k0 = blockIdx.y * 32;
  const int tx = threadIdx.x, ty = threadIdx.y;  // (32,8)
#pragma unroll
  for (int i = 0; i < 4; ++i)
    tile[ty + i * 8][tx] = in[(long)(k0 + ty + i * 8) * N + n0 + tx];
  __syncthreads();
#pragma unroll
  for (int i = 0; i < 4; ++i)
    out[(long)(n0 + ty + i * 8) * K + k0 + tx] = f2bf(tile[tx][ty + i * 8]);
}

// ------------------------------------------- transpose V: qkv v-part -> vt[bh][d][t]
__global__ __launch_bounds__(256) void transpose_v(const u16* __restrict__ qkv,
                                                   u16* __restrict__ vt) {
  __shared__ __align__(16) u16 tile[64][72];
  const int bid = blockIdx.x;
  const int tt = bid & 31;
  const int bh = bid >> 5;
  const int b = bh >> 4, hh = bh & 15;
  const long t0 = (long)tt * 64;
  const u16* src = qkv + ((long)b * 2048 + t0) * 3072 + 2048 + hh * 64;
#pragma unroll
  for (int i = 0; i < 2; ++i) {
    int e = (int)threadIdx.x + i * 256;  // 0..511
    int t = e >> 3, c = (e & 7) * 8;
    *(int4*)&tile[t][c] = *(const int4*)(src + (long)t * 3072 + c);
  }
  __syncthreads();
  u16* dst = vt + (long)bh * 64 * 2048 + t0;
#pragma unroll
  for (int i = 0; i < 2; ++i) {
    int e = (int)threadIdx.x + i * 256;
    int d = e >> 3, tc = (e & 7) * 8;
    union { u16 u[8]; int4 v; } pk;
#pragma unroll
    for (int j = 0; j < 8; ++j) pk.u[j] = tile[tc + j][d];
    *(int4*)(dst + (long)d * 2048 + tc) = pk.v;
  }
}

// ------------------------------------------- GEMM: C[M][N] = A[M][K] * Bt[N][K]^T + bias
// Double-buffered GLDS16 staging (T3 minimum 2-phase): STAGE(t+1) before
// compute(t), one __syncthreads per K-step.
template <int BM, int BN, int WN_WAVES, typename OutT>
__global__ __launch_bounds__(256) void gemm_bt(const u16* __restrict__ A,
                                               const u16* __restrict__ Bt,
                                               const float* __restrict__ bias,
                                               OutT* __restrict__ C,
                                               int M, int N, int K) {
  constexpr int WM = BM / (4 / WN_WAVES);  // rows per wave
  constexpr int WN = BN / WN_WAVES;
  constexpr int MF = WM / 16, NF = WN / 16;
  __shared__ __align__(16) u16 lA[2][BM * 32];
  __shared__ __align__(16) u16 lB[2][BN * 32];
  const int tid = (int)threadIdx.x;
  const int ln = tid & 63;
  const int w = tid >> 6;
  const int wr = w / WN_WAVES, wc = w % WN_WAVES;
  const int lr = ln & 15, lg = ln >> 4;
  const long mBase = (long)blockIdx.y * BM;
  const long nBase = (long)blockIdx.x * BN;

  f32x4 acc[MF][NF] = {};

  const int r0 = ln >> 2;        // 0..15 row within 16-row staging chunk
  const int c0 = (ln & 3) * 8;   // element offset within row

  auto stage = [&](int buf, int k0) {
#pragma unroll
    for (int i = 0; i < BM / 64; ++i) {
      const int br = (i * 4 + w) * 16;
      GLDS16(A + (mBase + br + r0) * K + k0 + c0, &lA[buf][br * 32]);
    }
#pragma unroll
    for (int i = 0; i < BN / 64; ++i) {
      const int br = (i * 4 + w) * 16;
      GLDS16(Bt + (nBase + br + r0) * K + k0 + c0, &lB[buf][br * 32]);
    }
  };

  stage(0, 0);
  __syncthreads();
  int cur = 0;
  for (int k0 = 0; k0 < K; k0 += 32) {
    if (k0 + 32 < K) stage(cur ^ 1, k0 + 32);  // in flight across compute
    bf16x8 af[MF], bfv[NF];
#pragma unroll
    for (int mi = 0; mi < MF; ++mi)
      af[mi] = *(const bf16x8*)&lA[cur][(wr * WM + mi * 16 + lr) * 32 + lg * 8];
#pragma unroll
    for (int ni = 0; ni < NF; ++ni)
      bfv[ni] = *(const bf16x8*)&lB[cur][(wc * WN + ni * 16 + lr) * 32 + lg * 8];
#pragma unroll
    for (int mi = 0; mi < MF; ++mi)
#pragma unroll
      for (int ni = 0; ni < NF; ++ni)
        acc[mi][ni] = __builtin_amdgcn_mfma_f32_16x16x32_bf16(af[mi], bfv[ni],
                                                              acc[mi][ni], 0, 0, 0);
    __syncthreads();  // drains vmcnt (next tile staged) + all frag reads done
    cur ^= 1;
  }

#pragma unroll
  for (int ni = 0; ni < NF; ++ni) {
    const long col = nBase + wc * WN + ni * 16 + lr;
    const float bv = bias[col];
#pragma unroll
    for (int mi = 0; mi < MF; ++mi) {
      const long row = mBase + wr * WM + mi * 16 + lg * 4;
#pragma unroll
      for (int j = 0; j < 4; ++j) {
        float v = acc[mi][ni][j] + bv;
        if constexpr (sizeof(OutT) == 2) {
          C[(row + j) * N + col] = (OutT)f2bf(v);
        } else {
          C[(row + j) * N + col] = v;
        }
      }
    }
  }
}

// ------------------------------------------- flash attention v4
// grid: 1024 blocks = 32 (b,h) * 32 q-tiles(64). 4 waves, 16 q-rows each.
// K/V double-buffered GLDS16 (pre-swizzled source + XOR reads), one barrier
// per KV-tile. Q pre-scaled by 0.125*log2e. P via XOR-swizzled per-wave LDS.
__global__ __launch_bounds__(256) void attn_fwd(const u16* __restrict__ qkv,
                                                const u16* __restrict__ vt,
                                                u16* __restrict__ outp) {
  __shared__ __align__(16) u16 lK[2][64 * 64];
  __shared__ __align__(16) u16 lV[2][64 * 64];
  __shared__ __align__(16) u16 lP[4][16 * 64];
  const int tid = (int)threadIdx.x;
  const int ln = tid & 63;
  const int w = tid >> 6;
  const int bid = (int)blockIdx.x;
  const int qt = bid & 31;
  const int bh = bid >> 5;
  const int b = bh >> 4;
  const int hh = bh & 15;
  const int lr = ln & 15;
  const int lg = ln >> 4;
  char* lPw = (char*)&lP[w][0];

  const float SCALE = 0.125f * 1.44269504088896f;  // 1/sqrt(64) * log2(e)

  // Q fragments, pre-scaled (S comes out of MFMA already in log2-scaled domain)
  const u16* Qp = qkv + ((long)(b * 2048 + qt * 64 + w * 16)) * 3072 + hh * 64;
  bf16x8 qf[2];
#pragma unroll
  for (int ks = 0; ks < 2; ++ks) {
    union { u16 u[8]; int4 i4; bf16x8 v; } in, ov;
    in.i4 = *(const int4*)(Qp + (long)lr * 3072 + ks * 32 + lg * 8);
#pragma unroll
    for (int e = 0; e < 8; ++e) {
      float f = __builtin_bit_cast(float, (unsigned)in.u[e] << 16) * SCALE;
      ov.u[e] = f2bf(f);
    }
    qf[ks] = ov.v;
  }

  f32x4 o[4] = {};
  float mrow[4], lsum[4];
#pragma unroll
  for (int j = 0; j < 4; ++j) { mrow[j] = -1e30f; lsum[j] = 0.f; }

  const u16* Kbase = qkv + ((long)b * 2048) * 3072 + 1024 + hh * 64;
  const u16* Vbase = vt + (long)bh * 64 * 2048;

  const int sr = ln >> 3;   // 0..7 row within 8-row staging chunk
  const int scm = ln & 7;   // chunk col 0..7

  auto stageKV = [&](int buf, int kv0) {
#pragma unroll
    for (int i = 0; i < 2; ++i) {
      const int br = (i * 4 + w) * 8;
      const int r = br + sr;
      const int cs = scm ^ (r & 7);
      GLDS16(Kbase + (long)(kv0 + r) * 3072 + cs * 8, &lK[buf][br * 64]);
      GLDS16(Vbase + (long)r * 2048 + kv0 + cs * 8, &lV[buf][br * 64]);
    }
  };

  stageKV(0, 0);
  __syncthreads();
  int cur = 0;
  for (int kt = 0; kt < 32; ++kt) {
    if (kt + 1 < 32) stageKV(cur ^ 1, (kt + 1) * 64);  // prefetch next tile

    // ---- QK^T: S[16 q][64 kv] (pre-scaled)
    f32x4 sc[4] = {};
#pragma unroll
    for (int nf = 0; nf < 4; ++nf) {
#pragma unroll
      for (int ks = 0; ks < 2; ++ks) {
        const int row = nf * 16 + lr;
        int off = (row * 64 + ks * 32 + lg * 8) * 2;
        off ^= (row & 7) << 4;
        const bf16x8 kf = *(const bf16x8*)((const char*)&lK[cur][0] + off);
        sc[nf] = __builtin_amdgcn_mfma_f32_16x16x32_bf16(qf[ks], kf, sc[nf], 0, 0, 0);
      }
    }

    // ---- online softmax (log2 domain), defer-max, deferred lsum
#pragma unroll
    for (int j = 0; j < 4; ++j) {
      const float s0 = sc[0][j], s1 = sc[1][j], s2 = sc[2][j], s3 = sc[3][j];
      float mx = fmaxf(fmaxf(s0, s1), fmaxf(s2, s3));
      mx = fmaxf(mx, __shfl_xor(mx, 1));
      mx = fmaxf(mx, __shfl_xor(mx, 2));
      mx = fmaxf(mx, __shfl_xor(mx, 4));
      mx = fmaxf(mx, __shfl_xor(mx, 8));
      if (!__all(mx <= mrow[j] + 8.0f)) {
        const float mnew = fmaxf(mrow[j], mx);
        const float sf = exp2f(mrow[j] - mnew);
        mrow[j] = mnew;
        lsum[j] *= sf;
        o[0][j] *= sf; o[1][j] *= sf; o[2][j] *= sf; o[3][j] *= sf;
      }
      const float m = mrow[j];
      const float p0 = exp2f(s0 - m);
      const float p1 = exp2f(s1 - m);
      const float p2 = exp2f(s2 - m);
      const float p3 = exp2f(s3 - m);
      lsum[j] += (p0 + p1) + (p2 + p3);
      const int prow = lg * 4 + j;
      const int rb = prow * 128, sw = (prow & 7) << 4;
      *(u16*)(lPw + ((rb + (0 * 16 + lr) * 2) ^ sw)) = bfc(p0);
      *(u16*)(lPw + ((rb + (1 * 16 + lr) * 2) ^ sw)) = bfc(p1);
      *(u16*)(lPw + ((rb + (2 * 16 + lr) * 2) ^ sw)) = bfc(p2);
      *(u16*)(lPw + ((rb + (3 * 16 + lr) * 2) ^ sw)) = bfc(p3);
    }
    asm volatile("s_waitcnt lgkmcnt(0)" ::: "memory");
    __builtin_amdgcn_sched_barrier(0);

    // ---- PV: O += P[16 q][64 kv] * Vt[64 d][64 kv]^T
    bf16x8 pf[2];
#pragma unroll
    for (int ks = 0; ks < 2; ++ks) {
      const int off = (lr * 128 + ks * 64 + lg * 16) ^ ((lr & 7) << 4);
      pf[ks] = *(const bf16x8*)(lPw + off);
    }
#pragma unroll
    for (int nf = 0; nf < 4; ++nf) {
#pragma unroll
      for (int ks = 0; ks < 2; ++ks) {
        const int row = nf * 16 + lr;
        int off = (row * 64 + ks * 32 + lg * 8) * 2;
        off ^= (row & 7) << 4;
        const bf16x8 vf = *(const bf16x8*)((const char*)&lV[cur][0] + off);
        o[nf] = __builtin_amdgcn_mfma_f32_16x16x32_bf16(pf[ks], vf, o[nf], 0, 0, 0);
      }
    }
    __syncthreads();  // next tile staged + everyone done with lK/lV[cur]
    cur ^= 1;
  }

  // ---- epilogue: reduce lsum across the 16-lane row group, normalize, store
#pragma unroll
  for (int j = 0; j < 4; ++j) {
    float rs = lsum[j];
    rs += __shfl_xor(rs, 1);
    rs += __shfl_xor(rs, 2);
    rs += __shfl_xor(rs, 4);
    rs += __shfl_xor(rs, 8);
    const float inv = 1.0f / rs;
    const int qrow = qt * 64 + w * 16 + lg * 4 + j;
    u16* orow = outp + ((long)(b * 2048 + qrow)) * 1024 + hh * 64;
#pragma unroll
    for (int nf = 0; nf < 4; ++nf)
      orow[nf * 16 + lr] = f2bf(o[nf][j] * inv);
  }
}

// ----------------------------------------------------------------------------
extern "C" void kernel_launch(void* const* d_in, const int* in_sizes, int n_in,
                              void* d_out, int out_size, void* d_ws, size_t ws_size,
                              hipStream_t stream) {
  (void)in_sizes; (void)n_in; (void)out_size;
  const float* x = (const float*)d_in[0];
  const float* b_attn = (const float*)d_in[2];
  const float* b_qkv = (const float*)d_in[4];
  const float* b_proj = (const float*)d_in[6];

  char* ws = (char*)d_ws;
  const size_t MB = 1024 * 1024;
  u16* xb   = (u16*)(ws + 0 * MB);    // 8 MB  [4096][1024]
  u16* hbuf = (u16*)(ws + 8 * MB);    // 8 MB  [4096][1024]
  u16* qkvb = (u16*)(ws + 16 * MB);   // 24 MB [4096][3072]
  u16* vtb  = (u16*)(ws + 40 * MB);   // 8 MB  [32][64][2048]
  u16* aout = (u16*)(ws + 48 * MB);   // 8 MB  [4096][1024]
  u16* wTa  = (u16*)(ws + 56 * MB);   // 2 MB  [1024][1024]
  u16* wTq  = (u16*)(ws + 58 * MB);   // 6 MB  [3072][1024]
  u16* wTp  = (u16*)(ws + 64 * MB);   // 2 MB  [1024][1024]
  if (ws_size < 66 * MB) return;

  cast_x<<<2048, 256, 0, stream>>>(x, xb);
  dim3 tcb(32, 8);
  transpose_cast<<<dim3(32, 32), tcb, 0, stream>>>((const float*)d_in[1], wTa, 1024, 1024);
  transpose_cast<<<dim3(96, 32), tcb, 0, stream>>>((const float*)d_in[3], wTq, 1024, 3072);
  transpose_cast<<<dim3(32, 32), tcb, 0, stream>>>((const float*)d_in[5], wTp, 1024, 1024);

  // h = x @ w_attn + b_attn        (64x128 tiles -> 512 blocks, 2/CU)
  gemm_bt<64, 128, 4, u16><<<dim3(8, 64), 256, 0, stream>>>(xb, wTa, b_attn, hbuf,
                                                            4096, 1024, 1024);
  // qkv = h @ w_qkv + b_qkv        (128x128 tiles -> 768 blocks, 3/CU)
  gemm_bt<128, 128, 2, u16><<<dim3(24, 32), 256, 0, stream>>>(hbuf, wTq, b_qkv, qkvb,
                                                              4096, 3072, 1024);
  transpose_v<<<1024, 256, 0, stream>>>(qkvb, vtb);
  attn_fwd<<<1024, 256, 0, stream>>>(qkvb, vtb, aout);
  // out = attn_out @ w_proj + b_proj (f32 out)
  gemm_bt<64, 128, 4, float><<<dim3(8, 64), 256, 0, stream>>>(aout, wTp, b_proj,
                                                              (float*)d_out,
                                                              4096, 1024, 1024);
}

// Round 6
// 203.645 us; speedup vs baseline: 1.3289x; 1.1833x over previous
//
#include <hip/hip_runtime.h>

typedef unsigned short u16;
typedef unsigned int u32;
typedef __bf16 bf16x8 __attribute__((ext_vector_type(8)));
typedef float f32x4 __attribute__((ext_vector_type(4)));
typedef float f32x16 __attribute__((ext_vector_type(16)));

typedef const __attribute__((address_space(1))) void* gcp_t;
typedef __attribute__((address_space(3))) void* lp_t;
#define GLDS16(g, l) __builtin_amdgcn_global_load_lds((gcp_t)(g), (lp_t)(l), 16, 0, 0)

__device__ __forceinline__ u16 f2bf(float f) {
  unsigned int u = __builtin_bit_cast(unsigned int, f);
  u += 0x7fffu + ((u >> 16) & 1u);
  return (u16)(u >> 16);
}
__device__ __forceinline__ u16 bfc(float f) {          // HW cvt (RNE)
  return __builtin_bit_cast(u16, (__bf16)f);
}
__device__ __forceinline__ u32 pkbf(float lo, float hi) {
  return (u32)bfc(lo) | ((u32)bfc(hi) << 16);
}

// ---------------------------------------------------------------- cast x -> bf16
__global__ __launch_bounds__(256) void cast_x(const float* __restrict__ in,
                                              u16* __restrict__ out) {
  long i = ((long)blockIdx.x * 256 + threadIdx.x) * 8;
  float4 a = *(const float4*)(in + i);
  float4 b = *(const float4*)(in + i + 4);
  union { u16 u[8]; int4 v; } pk;
  pk.u[0] = f2bf(a.x); pk.u[1] = f2bf(a.y); pk.u[2] = f2bf(a.z); pk.u[3] = f2bf(a.w);
  pk.u[4] = f2bf(b.x); pk.u[5] = f2bf(b.y); pk.u[6] = f2bf(b.z); pk.u[7] = f2bf(b.w);
  *(int4*)(out + i) = pk.v;
}

// ------------------------------------------- transpose+cast weights: [K][N] f32 -> [N][K] bf16
__global__ __launch_bounds__(256) void transpose_cast(const float* __restrict__ in,
                                                      u16* __restrict__ out,
                                                      int K, int N) {
  __shared__ float tile[32][33];
  const int n0 = blockIdx.x * 32, k0 = blockIdx.y * 32;
  const int tx = threadIdx.x, ty = threadIdx.y;  // (32,8)
#pragma unroll
  for (int i = 0; i < 4; ++i)
    tile[ty + i * 8][tx] = in[(long)(k0 + ty + i * 8) * N + n0 + tx];
  __syncthreads();
#pragma unroll
  for (int i = 0; i < 4; ++i)
    out[(long)(n0 + ty + i * 8) * K + k0 + tx] = f2bf(tile[tx][ty + i * 8]);
}

// ------------------------------------------- transpose V: qkv v-part -> vt[bh][d][t]
__global__ __launch_bounds__(256) void transpose_v(const u16* __restrict__ qkv,
                                                   u16* __restrict__ vt) {
  __shared__ __align__(16) u16 tile[64][72];
  const int bid = blockIdx.x;
  const int tt = bid & 31;
  const int bh = bid >> 5;
  const int b = bh >> 4, hh = bh & 15;
  const long t0 = (long)tt * 64;
  const u16* src = qkv + ((long)b * 2048 + t0) * 3072 + 2048 + hh * 64;
#pragma unroll
  for (int i = 0; i < 2; ++i) {
    int e = (int)threadIdx.x + i * 256;  // 0..511
    int t = e >> 3, c = (e & 7) * 8;
    *(int4*)&tile[t][c] = *(const int4*)(src + (long)t * 3072 + c);
  }
  __syncthreads();
  u16* dst = vt + (long)bh * 64 * 2048 + t0;
#pragma unroll
  for (int i = 0; i < 2; ++i) {
    int e = (int)threadIdx.x + i * 256;
    int d = e >> 3, tc = (e & 7) * 8;
    union { u16 u[8]; int4 v; } pk;
#pragma unroll
    for (int j = 0; j < 8; ++j) pk.u[j] = tile[tc + j][d];
    *(int4*)(dst + (long)d * 2048 + tc) = pk.v;
  }
}

// ------------------------------------------- GEMM: C[M][N] = A[M][K] * Bt[N][K]^T + bias
// Double-buffered GLDS16 staging (T3 minimum 2-phase).
template <int BM, int BN, int WN_WAVES, typename OutT>
__global__ __launch_bounds__(256) void gemm_bt(const u16* __restrict__ A,
                                               const u16* __restrict__ Bt,
                                               const float* __restrict__ bias,
                                               OutT* __restrict__ C,
                                               int M, int N, int K) {
  constexpr int WM = BM / (4 / WN_WAVES);
  constexpr int WN = BN / WN_WAVES;
  constexpr int MF = WM / 16, NF = WN / 16;
  __shared__ __align__(16) u16 lA[2][BM * 32];
  __shared__ __align__(16) u16 lB[2][BN * 32];
  const int tid = (int)threadIdx.x;
  const int ln = tid & 63;
  const int w = tid >> 6;
  const int wr = w / WN_WAVES, wc = w % WN_WAVES;
  const int lr = ln & 15, lg = ln >> 4;
  const long mBase = (long)blockIdx.y * BM;
  const long nBase = (long)blockIdx.x * BN;

  f32x4 acc[MF][NF] = {};

  const int r0 = ln >> 2;
  const int c0 = (ln & 3) * 8;

  auto stage = [&](int buf, int k0) {
#pragma unroll
    for (int i = 0; i < BM / 64; ++i) {
      const int br = (i * 4 + w) * 16;
      GLDS16(A + (mBase + br + r0) * K + k0 + c0, &lA[buf][br * 32]);
    }
#pragma unroll
    for (int i = 0; i < BN / 64; ++i) {
      const int br = (i * 4 + w) * 16;
      GLDS16(Bt + (nBase + br + r0) * K + k0 + c0, &lB[buf][br * 32]);
    }
  };

  stage(0, 0);
  __syncthreads();
  int cur = 0;
  for (int k0 = 0; k0 < K; k0 += 32) {
    if (k0 + 32 < K) stage(cur ^ 1, k0 + 32);
    bf16x8 af[MF], bfv[NF];
#pragma unroll
    for (int mi = 0; mi < MF; ++mi)
      af[mi] = *(const bf16x8*)&lA[cur][(wr * WM + mi * 16 + lr) * 32 + lg * 8];
#pragma unroll
    for (int ni = 0; ni < NF; ++ni)
      bfv[ni] = *(const bf16x8*)&lB[cur][(wc * WN + ni * 16 + lr) * 32 + lg * 8];
#pragma unroll
    for (int mi = 0; mi < MF; ++mi)
#pragma unroll
      for (int ni = 0; ni < NF; ++ni)
        acc[mi][ni] = __builtin_amdgcn_mfma_f32_16x16x32_bf16(af[mi], bfv[ni],
                                                              acc[mi][ni], 0, 0, 0);
    __syncthreads();
    cur ^= 1;
  }

#pragma unroll
  for (int ni = 0; ni < NF; ++ni) {
    const long col = nBase + wc * WN + ni * 16 + lr;
    const float bv = bias[col];
#pragma unroll
    for (int mi = 0; mi < MF; ++mi) {
      const long row = mBase + wr * WM + mi * 16 + lg * 4;
#pragma unroll
      for (int j = 0; j < 4; ++j) {
        float v = acc[mi][ni][j] + bv;
        if constexpr (sizeof(OutT) == 2) {
          C[(row + j) * N + col] = (OutT)f2bf(v);
        } else {
          C[(row + j) * N + col] = v;
        }
      }
    }
  }
}

// ------------------------------------------- flash attention v5: swapped-QK 32x32
// grid: 512 blocks = 32 (b,h) * 16 q-tiles(128). 4 waves, 32 q-rows each.
// S^T = mfma(K,Q): lane owns P[q=lane&31][kv in crow-set] in regs; softmax is
// in-lane tree + one shfl_xor(32). P->PV B-frag via in-reg pack + half-swap.
// O^T = mfma(Vt, P^T): O's q = lane&31 -> rescale/normalize lane-local.
__global__ __launch_bounds__(256) void attn_fwd(const u16* __restrict__ qkv,
                                                const u16* __restrict__ vt,
                                                u16* __restrict__ outp) {
  __shared__ __align__(16) u16 smem[2][2][64 * 64];  // [buf][K/V][64*64] 32 KB
  const int tid = (int)threadIdx.x;
  const int ln = tid & 63;
  const int l31 = tid & 31;
  const int hiH = (tid >> 5) & 1;
  const int w = tid >> 6;
  const int bid = (int)blockIdx.x;
  const int qt = bid & 15;
  const int bh = bid >> 4;
  const int b = bh >> 4;
  const int hh = bh & 15;

  const float SCALE = 0.125f * 1.44269504088896f;  // 1/sqrt(64) * log2(e)

  // ---- Q fragments (B-operand for swapped QK): col=q=l31, k=d, pre-scaled
  const long qrow = (long)(b * 2048 + qt * 128 + w * 32 + l31);
  const u16* Qp = qkv + qrow * 3072 + hh * 64;
  bf16x8 qf[4];
#pragma unroll
  for (int ks = 0; ks < 4; ++ks) {
    union { u16 u[8]; int4 i4; bf16x8 v; } in, ov;
    in.i4 = *(const int4*)(Qp + ks * 16 + hiH * 8);
#pragma unroll
    for (int e = 0; e < 8; ++e) {
      float f = __builtin_bit_cast(float, (u32)in.u[e] << 16) * SCALE;
      ov.u[e] = f2bf(f);
    }
    qf[ks] = ov.v;
  }

  f32x16 o[2] = {};
  float mrow = -1e30f, lsum = 0.f;

  const u16* Kbase = qkv + ((long)b * 2048) * 3072 + 1024 + hh * 64;
  const u16* Vbase = vt + (long)bh * 64 * 2048;

  const int sr = ln >> 3;   // 0..7 row within 8-row staging chunk
  const int scm = ln & 7;   // chunk col

  auto stageKV = [&](int buf, int kv0) {
#pragma unroll
    for (int i = 0; i < 2; ++i) {
      const int br = (i * 4 + w) * 8;
      const int r = br + sr;
      const int cs = scm ^ (r & 7);
      GLDS16(Kbase + (long)(kv0 + r) * 3072 + cs * 8, &smem[buf][0][br * 64]);
      GLDS16(Vbase + (long)r * 2048 + kv0 + cs * 8, &smem[buf][1][br * 64]);
    }
  };

  stageKV(0, 0);
  __syncthreads();
  int cur = 0;
  for (int kt = 0; kt < 32; ++kt) {
    if (kt + 1 < 32) stageKV(cur ^ 1, (kt + 1) * 64);
    const char* lK = (const char*)&smem[cur][0][0];
    const char* lV = (const char*)&smem[cur][1][0];

    // ---- QK^T (swapped): st[t][reg] = S^T[kv=crow(reg,hiH)+t*32][q=l31]
    f32x16 st[2] = {};
#pragma unroll
    for (int t = 0; t < 2; ++t) {
#pragma unroll
      for (int ks = 0; ks < 4; ++ks) {
        const int r = t * 32 + l31;
        int off = (r * 64 + ks * 16 + hiH * 8) * 2;
        off ^= (r & 7) << 4;
        const bf16x8 kf = *(const bf16x8*)(lK + off);
        st[t] = __builtin_amdgcn_mfma_f32_32x32x16_bf16(kf, qf[ks], st[t], 0, 0, 0);
      }
    }

    // ---- softmax: in-lane max tree over 32 + one cross-half shfl
    float tm[16];
#pragma unroll
    for (int r = 0; r < 16; ++r) tm[r] = fmaxf(st[0][r], st[1][r]);
#pragma unroll
    for (int s = 8; s > 0; s >>= 1)
#pragma unroll
      for (int r = 0; r < 8; ++r)
        if (r < s) tm[r] = fmaxf(tm[r], tm[r + s]);
    float mx = fmaxf(tm[0], __shfl_xor(tm[0], 32));

    if (!__all(mx <= mrow + 8.0f)) {
      const float mnew = fmaxf(mrow, mx);
      const float sf = exp2f(mrow - mnew);
      mrow = mnew;
      lsum *= sf;
      o[0] *= sf;
      o[1] *= sf;
    }

    // P = exp2(st - m) in place; accumulate per-lane partial lsum
#pragma unroll
    for (int t = 0; t < 2; ++t)
#pragma unroll
      for (int r = 0; r < 16; ++r) st[t][r] = exp2f(st[t][r] - mrow);
    float ts[16];
#pragma unroll
    for (int r = 0; r < 16; ++r) ts[r] = st[0][r] + st[1][r];
#pragma unroll
    for (int s = 8; s > 0; s >>= 1)
#pragma unroll
      for (int r = 0; r < 8; ++r)
        if (r < s) ts[r] += ts[r + s];
    lsum += ts[0];

    // ---- pack P -> PV B-frags (P^T: col=q=l31, k=kv) via half-swap exchange
    bf16x8 pa[4];
#pragma unroll
    for (int t = 0; t < 2; ++t) {
#pragma unroll
      for (int g = 0; g < 2; ++g) {
        const int bse = g * 8;
        const u32 A = pkbf(st[t][bse + 0], st[t][bse + 1]);
        const u32 B = pkbf(st[t][bse + 2], st[t][bse + 3]);
        const u32 C = pkbf(st[t][bse + 4], st[t][bse + 5]);
        const u32 D = pkbf(st[t][bse + 6], st[t][bse + 7]);
        const u32 sA = __shfl_xor((int)A, 32);
        const u32 sB = __shfl_xor((int)B, 32);
        const u32 sC = __shfl_xor((int)C, 32);
        const u32 sD = __shfl_xor((int)D, 32);
        union { u32 wv[4]; bf16x8 v; } u;
        u.wv[0] = hiH ? sC : A;
        u.wv[1] = hiH ? sD : B;
        u.wv[2] = hiH ? C : sA;
        u.wv[3] = hiH ? D : sB;
        pa[t * 2 + g] = u.v;
      }
    }

    // ---- PV: O^T[d][q] += Vt[d][kv] * P^T[kv][q]
#pragma unroll
    for (int dt = 0; dt < 2; ++dt) {
#pragma unroll
      for (int ks2 = 0; ks2 < 4; ++ks2) {
        const int r = dt * 32 + l31;
        int off = (r * 64 + ks2 * 16 + hiH * 8) * 2;
        off ^= (r & 7) << 4;
        const bf16x8 vf = *(const bf16x8*)(lV + off);
        o[dt] = __builtin_amdgcn_mfma_f32_32x32x16_bf16(vf, pa[ks2], o[dt], 0, 0, 0);
      }
    }
    __syncthreads();
    cur ^= 1;
  }

  // ---- epilogue: normalize (lane-local), transpose via LDS, coalesced store
  __syncthreads();  // all waves done reading staging LDS
  u16* T = (u16*)smem + w * (32 * 72);
  const float linv = 1.0f / (lsum + __shfl_xor(lsum, 32));
#pragma unroll
  for (int dt = 0; dt < 2; ++dt)
#pragma unroll
    for (int r = 0; r < 16; ++r) {
      const int d = (r & 3) + 8 * (r >> 2) + 4 * hiH + dt * 32;
      T[l31 * 72 + d] = bfc(o[dt][r] * linv);
    }
  asm volatile("s_waitcnt lgkmcnt(0)" ::: "memory");
  __builtin_amdgcn_sched_barrier(0);
  {
    const int rr = ln >> 1;
    const int c0 = (ln & 1) * 32;
    u16* orow = outp + ((long)(b * 2048 + qt * 128 + w * 32 + rr)) * 1024 + hh * 64 + c0;
#pragma unroll
    for (int i = 0; i < 4; ++i)
      *(int4*)(orow + i * 8) = *(const int4*)&T[rr * 72 + c0 + i * 8];
  }
}

// ----------------------------------------------------------------------------
extern "C" void kernel_launch(void* const* d_in, const int* in_sizes, int n_in,
                              void* d_out, int out_size, void* d_ws, size_t ws_size,
                              hipStream_t stream) {
  (void)in_sizes; (void)n_in; (void)out_size;
  const float* x = (const float*)d_in[0];
  const float* b_attn = (const float*)d_in[2];
  const float* b_qkv = (const float*)d_in[4];
  const float* b_proj = (const float*)d_in[6];

  char* ws = (char*)d_ws;
  const size_t MB = 1024 * 1024;
  u16* xb   = (u16*)(ws + 0 * MB);
  u16* hbuf = (u16*)(ws + 8 * MB);
  u16* qkvb = (u16*)(ws + 16 * MB);
  u16* vtb  = (u16*)(ws + 40 * MB);
  u16* aout = (u16*)(ws + 48 * MB);
  u16* wTa  = (u16*)(ws + 56 * MB);
  u16* wTq  = (u16*)(ws + 58 * MB);
  u16* wTp  = (u16*)(ws + 64 * MB);
  if (ws_size < 66 * MB) return;

  cast_x<<<2048, 256, 0, stream>>>(x, xb);
  dim3 tcb(32, 8);
  transpose_cast<<<dim3(32, 32), tcb, 0, stream>>>((const float*)d_in[1], wTa, 1024, 1024);
  transpose_cast<<<dim3(96, 32), tcb, 0, stream>>>((const float*)d_in[3], wTq, 1024, 3072);
  transpose_cast<<<dim3(32, 32), tcb, 0, stream>>>((const float*)d_in[5], wTp, 1024, 1024);

  gemm_bt<64, 128, 4, u16><<<dim3(8, 64), 256, 0, stream>>>(xb, wTa, b_attn, hbuf,
                                                            4096, 1024, 1024);
  gemm_bt<128, 128, 2, u16><<<dim3(24, 32), 256, 0, stream>>>(hbuf, wTq, b_qkv, qkvb,
                                                              4096, 3072, 1024);
  transpose_v<<<1024, 256, 0, stream>>>(qkvb, vtb);
  attn_fwd<<<512, 256, 0, stream>>>(qkvb, vtb, aout);
  gemm_bt<64, 128, 4, float><<<dim3(8, 64), 256, 0, stream>>>(aout, wTp, b_proj,
                                                              (float*)d_out,
                                                              4096, 1024, 1024);
}

// Round 7
// 170.171 us; speedup vs baseline: 1.5903x; 1.1967x over previous
//
#include <hip/hip_runtime.h>

typedef unsigned short u16;
typedef unsigned int u32;
typedef __bf16 bf16x8 __attribute__((ext_vector_type(8)));
typedef float f32x4 __attribute__((ext_vector_type(4)));
typedef float f32x16 __attribute__((ext_vector_type(16)));
typedef unsigned uint2v __attribute__((ext_vector_type(2)));

typedef const __attribute__((address_space(1))) void* gcp_t;
typedef __attribute__((address_space(3))) void* lp_t;
#define GLDS16(g, l) __builtin_amdgcn_global_load_lds((gcp_t)(g), (lp_t)(l), 16, 0, 0)

__device__ __forceinline__ u16 f2bf(float f) {
  unsigned int u = __builtin_bit_cast(unsigned int, f);
  u += 0x7fffu + ((u >> 16) & 1u);
  return (u16)(u >> 16);
}
__device__ __forceinline__ u16 bfc(float f) {          // HW cvt (RNE)
  return __builtin_bit_cast(u16, (__bf16)f);
}
__device__ __forceinline__ u32 pkbf(float lo, float hi) {
  return (u32)bfc(lo) | ((u32)bfc(hi) << 16);
}
__device__ __forceinline__ float ex2(float x) {
  return __builtin_amdgcn_exp2f(x);                    // raw v_exp_f32
}

// ---------------------------------------------------------------- cast x -> bf16
__global__ __launch_bounds__(256) void cast_x(const float* __restrict__ in,
                                              u16* __restrict__ out) {
  long i = ((long)blockIdx.x * 256 + threadIdx.x) * 8;
  float4 a = *(const float4*)(in + i);
  float4 b = *(const float4*)(in + i + 4);
  union { u16 u[8]; int4 v; } pk;
  pk.u[0] = f2bf(a.x); pk.u[1] = f2bf(a.y); pk.u[2] = f2bf(a.z); pk.u[3] = f2bf(a.w);
  pk.u[4] = f2bf(b.x); pk.u[5] = f2bf(b.y); pk.u[6] = f2bf(b.z); pk.u[7] = f2bf(b.w);
  *(int4*)(out + i) = pk.v;
}

// ------------------------------------------- transpose+cast weights: [K][N] f32 -> [N][K] bf16
__global__ __launch_bounds__(256) void transpose_cast(const float* __restrict__ in,
                                                      u16* __restrict__ out,
                                                      int K, int N) {
  __shared__ float tile[32][33];
  const int n0 = blockIdx.x * 32, k0 = blockIdx.y * 32;
  const int tx = threadIdx.x, ty = threadIdx.y;  // (32,8)
#pragma unroll
  for (int i = 0; i < 4; ++i)
    tile[ty + i * 8][tx] = in[(long)(k0 + ty + i * 8) * N + n0 + tx];
  __syncthreads();
#pragma unroll
  for (int i = 0; i < 4; ++i)
    out[(long)(n0 + ty + i * 8) * K + k0 + tx] = f2bf(tile[tx][ty + i * 8]);
}

// ------------------------------------------- transpose V: qkv v-part -> vt[bh][d][t]
__global__ __launch_bounds__(256) void transpose_v(const u16* __restrict__ qkv,
                                                   u16* __restrict__ vt) {
  __shared__ __align__(16) u16 tile[64][72];
  const int bid = blockIdx.x;
  const int tt = bid & 31;
  const int bh = bid >> 5;
  const int b = bh >> 4, hh = bh & 15;
  const long t0 = (long)tt * 64;
  const u16* src = qkv + ((long)b * 2048 + t0) * 3072 + 2048 + hh * 64;
#pragma unroll
  for (int i = 0; i < 2; ++i) {
    int e = (int)threadIdx.x + i * 256;  // 0..511
    int t = e >> 3, c = (e & 7) * 8;
    *(int4*)&tile[t][c] = *(const int4*)(src + (long)t * 3072 + c);
  }
  __syncthreads();
  u16* dst = vt + (long)bh * 64 * 2048 + t0;
#pragma unroll
  for (int i = 0; i < 2; ++i) {
    int e = (int)threadIdx.x + i * 256;
    int d = e >> 3, tc = (e & 7) * 8;
    union { u16 u[8]; int4 v; } pk;
#pragma unroll
    for (int j = 0; j < 8; ++j) pk.u[j] = tile[tc + j][d];
    *(int4*)(dst + (long)d * 2048 + tc) = pk.v;
  }
}

// ------------------------------------------- GEMM: C[M][N] = A[M][K] * Bt[N][K]^T + bias
template <int BM, int BN, int WN_WAVES, typename OutT>
__global__ __launch_bounds__(256) void gemm_bt(const u16* __restrict__ A,
                                               const u16* __restrict__ Bt,
                                               const float* __restrict__ bias,
                                               OutT* __restrict__ C,
                                               int M, int N, int K) {
  constexpr int WM = BM / (4 / WN_WAVES);
  constexpr int WN = BN / WN_WAVES;
  constexpr int MF = WM / 16, NF = WN / 16;
  __shared__ __align__(16) u16 lA[2][BM * 32];
  __shared__ __align__(16) u16 lB[2][BN * 32];
  const int tid = (int)threadIdx.x;
  const int ln = tid & 63;
  const int w = tid >> 6;
  const int wr = w / WN_WAVES, wc = w % WN_WAVES;
  const int lr = ln & 15, lg = ln >> 4;
  const long mBase = (long)blockIdx.y * BM;
  const long nBase = (long)blockIdx.x * BN;

  f32x4 acc[MF][NF] = {};

  const int r0 = ln >> 2;
  const int c0 = (ln & 3) * 8;

  auto stage = [&](int buf, int k0) {
#pragma unroll
    for (int i = 0; i < BM / 64; ++i) {
      const int br = (i * 4 + w) * 16;
      GLDS16(A + (mBase + br + r0) * K + k0 + c0, &lA[buf][br * 32]);
    }
#pragma unroll
    for (int i = 0; i < BN / 64; ++i) {
      const int br = (i * 4 + w) * 16;
      GLDS16(Bt + (nBase + br + r0) * K + k0 + c0, &lB[buf][br * 32]);
    }
  };

  stage(0, 0);
  __syncthreads();
  int cur = 0;
  for (int k0 = 0; k0 < K; k0 += 32) {
    if (k0 + 32 < K) stage(cur ^ 1, k0 + 32);
    bf16x8 af[MF], bfv[NF];
#pragma unroll
    for (int mi = 0; mi < MF; ++mi)
      af[mi] = *(const bf16x8*)&lA[cur][(wr * WM + mi * 16 + lr) * 32 + lg * 8];
#pragma unroll
    for (int ni = 0; ni < NF; ++ni)
      bfv[ni] = *(const bf16x8*)&lB[cur][(wc * WN + ni * 16 + lr) * 32 + lg * 8];
#pragma unroll
    for (int mi = 0; mi < MF; ++mi)
#pragma unroll
      for (int ni = 0; ni < NF; ++ni)
        acc[mi][ni] = __builtin_amdgcn_mfma_f32_16x16x32_bf16(af[mi], bfv[ni],
                                                              acc[mi][ni], 0, 0, 0);
    __syncthreads();
    cur ^= 1;
  }

#pragma unroll
  for (int ni = 0; ni < NF; ++ni) {
    const long col = nBase + wc * WN + ni * 16 + lr;
    const float bv = bias[col];
#pragma unroll
    for (int mi = 0; mi < MF; ++mi) {
      const long row = mBase + wr * WM + mi * 16 + lg * 4;
#pragma unroll
      for (int j = 0; j < 4; ++j) {
        float v = acc[mi][ni][j] + bv;
        if constexpr (sizeof(OutT) == 2) {
          C[(row + j) * N + col] = (OutT)f2bf(v);
        } else {
          C[(row + j) * N + col] = v;
        }
      }
    }
  }
}

// ------------------------------------------- flash attention v6: KV-split 8-wave
// grid: 512 blocks (32 bh x 16 qt128), 512 threads. Wave w: group g=w>>2 covers
// KV tiles [g*16, g*16+16), q-block qw=w&3 (32 rows). Swapped-QK 32x32 MFMA,
// in-register softmax (native exp2), permlane32_swap P-pack, per-group dbuf
// LDS staging. End: groups merge (m,l,O) partials through LDS, lower waves
// normalize + transpose + store.
__global__ __launch_bounds__(512, 4) void attn_fwd(const u16* __restrict__ qkv,
                                                   const u16* __restrict__ vt,
                                                   u16* __restrict__ outp) {
  __shared__ __align__(16) u16 smem[2][2][2][64 * 64];  // [grp][buf][K/V] 64 KB
  const int tid = (int)threadIdx.x;
  const int ln = tid & 63;
  const int l31 = tid & 31;
  const int hiH = (tid >> 5) & 1;
  const int w = tid >> 6;       // 0..7
  const int g = w >> 2;         // KV-half
  const int qw = w & 3;         // q-block
  const int bid = (int)blockIdx.x;
  const int qt = bid & 15;
  const int bh = bid >> 4;
  const int b = bh >> 4;
  const int hh = bh & 15;

  const float SCALE = 0.125f * 1.44269504088896f;  // 1/sqrt(64) * log2(e)

  // ---- Q fragments (B-operand for swapped QK): col=q=l31, k=d, pre-scaled
  const long qrow = (long)(b * 2048 + qt * 128 + qw * 32 + l31);
  const u16* Qp = qkv + qrow * 3072 + hh * 64;
  bf16x8 qf[4];
#pragma unroll
  for (int ks = 0; ks < 4; ++ks) {
    union { u16 u[8]; int4 i4; bf16x8 v; } in, ov;
    in.i4 = *(const int4*)(Qp + ks * 16 + hiH * 8);
#pragma unroll
    for (int e = 0; e < 8; ++e) {
      float f = __builtin_bit_cast(float, (u32)in.u[e] << 16) * SCALE;
      ov.u[e] = f2bf(f);
    }
    qf[ks] = ov.v;
  }

  f32x16 o[2] = {};
  float mrow = -1e30f, lsum = 0.f;

  const u16* Kbase = qkv + ((long)b * 2048) * 3072 + 1024 + hh * 64;
  const u16* Vbase = vt + (long)bh * 64 * 2048;

  const int sr = ln >> 3;
  const int scm = ln & 7;

  auto stageKV = [&](int buf, int t) {
    const int kv0 = (g * 16 + t) * 64;
#pragma unroll
    for (int i = 0; i < 2; ++i) {
      const int br = (i * 4 + qw) * 8;
      const int r = br + sr;
      const int cs = scm ^ (r & 7);
      GLDS16(Kbase + (long)(kv0 + r) * 3072 + cs * 8, &smem[g][buf][0][br * 64]);
      GLDS16(Vbase + (long)r * 2048 + kv0 + cs * 8, &smem[g][buf][1][br * 64]);
    }
  };

  stageKV(0, 0);
  __syncthreads();
  int cur = 0;
  for (int kt = 0; kt < 16; ++kt) {
    if (kt + 1 < 16) stageKV(cur ^ 1, kt + 1);
    const char* lK = (const char*)&smem[g][cur][0][0];
    const char* lV = (const char*)&smem[g][cur][1][0];

    // ---- QK^T (swapped): st[t][reg] = S^T[kv][q=l31]
    f32x16 st[2] = {};
#pragma unroll
    for (int t = 0; t < 2; ++t) {
#pragma unroll
      for (int ks = 0; ks < 4; ++ks) {
        const int r = t * 32 + l31;
        int off = (r * 64 + ks * 16 + hiH * 8) * 2;
        off ^= (r & 7) << 4;
        const bf16x8 kf = *(const bf16x8*)(lK + off);
        st[t] = __builtin_amdgcn_mfma_f32_32x32x16_bf16(kf, qf[ks], st[t], 0, 0, 0);
      }
    }

    // ---- softmax: in-lane max tree + one cross-half shfl
    float tm[16];
#pragma unroll
    for (int r = 0; r < 16; ++r) tm[r] = fmaxf(st[0][r], st[1][r]);
#pragma unroll
    for (int s = 8; s > 0; s >>= 1)
#pragma unroll
      for (int r = 0; r < 8; ++r)
        if (r < s) tm[r] = fmaxf(tm[r], tm[r + s]);
    float mx = fmaxf(tm[0], __shfl_xor(tm[0], 32));

    if (!__all(mx <= mrow + 8.0f)) {
      const float mnew = fmaxf(mrow, mx);
      const float sf = ex2(mrow - mnew);
      mrow = mnew;
      lsum *= sf;
      o[0] *= sf;
      o[1] *= sf;
    }

#pragma unroll
    for (int t = 0; t < 2; ++t)
#pragma unroll
      for (int r = 0; r < 16; ++r) st[t][r] = ex2(st[t][r] - mrow);
    float ts[16];
#pragma unroll
    for (int r = 0; r < 16; ++r) ts[r] = st[0][r] + st[1][r];
#pragma unroll
    for (int s = 8; s > 0; s >>= 1)
#pragma unroll
      for (int r = 0; r < 8; ++r)
        if (r < s) ts[r] += ts[r + s];
    lsum += ts[0];

    // ---- pack P -> PV B-frags via permlane32_swap (one swap fills 2 words)
    bf16x8 pa[4];
#pragma unroll
    for (int t = 0; t < 2; ++t) {
#pragma unroll
      for (int gg = 0; gg < 2; ++gg) {
        const int bse = gg * 8;
        u32 A = pkbf(st[t][bse + 0], st[t][bse + 1]);
        u32 B = pkbf(st[t][bse + 2], st[t][bse + 3]);
        u32 C = pkbf(st[t][bse + 4], st[t][bse + 5]);
        u32 D = pkbf(st[t][bse + 6], st[t][bse + 7]);
        union { u32 wv[4]; bf16x8 v; } u;
#if __has_builtin(__builtin_amdgcn_permlane32_swap)
        uint2v r0 = __builtin_amdgcn_permlane32_swap(A, C, false, false);
        uint2v r1 = __builtin_amdgcn_permlane32_swap(B, D, false, false);
        u.wv[0] = r0[0]; u.wv[1] = r1[0]; u.wv[2] = r0[1]; u.wv[3] = r1[1];
#else
        const u32 sA = __shfl_xor((int)A, 32);
        const u32 sB = __shfl_xor((int)B, 32);
        const u32 sC = __shfl_xor((int)C, 32);
        const u32 sD = __shfl_xor((int)D, 32);
        u.wv[0] = hiH ? sC : A;
        u.wv[1] = hiH ? sD : B;
        u.wv[2] = hiH ? C : sA;
        u.wv[3] = hiH ? D : sB;
#endif
        pa[t * 2 + gg] = u.v;
      }
    }

    // ---- PV: O^T[d][q] += Vt[d][kv] * P^T[kv][q]
#pragma unroll
    for (int dt = 0; dt < 2; ++dt) {
#pragma unroll
      for (int ks2 = 0; ks2 < 4; ++ks2) {
        const int r = dt * 32 + l31;
        int off = (r * 64 + ks2 * 16 + hiH * 8) * 2;
        off ^= (r & 7) << 4;
        const bf16x8 vf = *(const bf16x8*)(lV + off);
        o[dt] = __builtin_amdgcn_mfma_f32_32x32x16_bf16(vf, pa[ks2], o[dt], 0, 0, 0);
      }
    }
    __syncthreads();
    cur ^= 1;
  }

  // ---- merge the two KV-half partials (through LDS), normalize, store
  const float lsum_tot = lsum + __shfl_xor(lsum, 32);
  float* PO = (float*)&smem[0][0][0][0];                 // 32 KB: 4 upper waves' O
  float* MLf = (float*)((char*)PO + 32768);              // 4 KB: m,l per lane

  if (g == 1) {
    float* dst = PO + (w - 4) * 2048 + ln * 32;
#pragma unroll
    for (int dt = 0; dt < 2; ++dt)
#pragma unroll
      for (int q4 = 0; q4 < 4; ++q4) {
        f32x4 c;
#pragma unroll
        for (int j = 0; j < 4; ++j) c[j] = o[dt][q4 * 4 + j];
        *(f32x4*)(dst + dt * 16 + q4 * 4) = c;
      }
    MLf[(w - 4) * 128 + ln * 2] = mrow;
    MLf[(w - 4) * 128 + ln * 2 + 1] = lsum_tot;
  }
  __syncthreads();
  if (g == 0) {
    const float m1 = MLf[w * 128 + ln * 2];
    const float l1 = MLf[w * 128 + ln * 2 + 1];
    const float* src = PO + w * 2048 + ln * 32;
    const float m = fmaxf(mrow, m1);
    const float a0 = ex2(mrow - m);
    const float a1 = ex2(m1 - m);
    const float linv = 1.0f / (lsum_tot * a0 + l1 * a1);
    u16* T = (u16*)((char*)smem + 36864) + w * (32 * 72);  // 18 KB region
#pragma unroll
    for (int dt = 0; dt < 2; ++dt) {
      float o1[16];
#pragma unroll
      for (int q4 = 0; q4 < 4; ++q4) {
        const f32x4 c = *(const f32x4*)(src + dt * 16 + q4 * 4);
#pragma unroll
        for (int j = 0; j < 4; ++j) o1[q4 * 4 + j] = c[j];
      }
#pragma unroll
      for (int r = 0; r < 16; ++r) {
        const float v = (o[dt][r] * a0 + o1[r] * a1) * linv;
        const int d = (r & 3) + 8 * (r >> 2) + 4 * hiH + dt * 32;
        T[l31 * 72 + d] = bfc(v);
      }
    }
    asm volatile("s_waitcnt lgkmcnt(0)" ::: "memory");
    __builtin_amdgcn_sched_barrier(0);
    const int rr = ln >> 1;
    const int c0 = (ln & 1) * 32;
    u16* orow = outp + ((long)(b * 2048 + qt * 128 + w * 32 + rr)) * 1024 + hh * 64 + c0;
#pragma unroll
    for (int i = 0; i < 4; ++i)
      *(int4*)(orow + i * 8) = *(const int4*)&T[rr * 72 + c0 + i * 8];
  }
}

// ----------------------------------------------------------------------------
extern "C" void kernel_launch(void* const* d_in, const int* in_sizes, int n_in,
                              void* d_out, int out_size, void* d_ws, size_t ws_size,
                              hipStream_t stream) {
  (void)in_sizes; (void)n_in; (void)out_size;
  const float* x = (const float*)d_in[0];
  const float* b_attn = (const float*)d_in[2];
  const float* b_qkv = (const float*)d_in[4];
  const float* b_proj = (const float*)d_in[6];

  char* ws = (char*)d_ws;
  const size_t MB = 1024 * 1024;
  u16* xb   = (u16*)(ws + 0 * MB);
  u16* hbuf = (u16*)(ws + 8 * MB);
  u16* qkvb = (u16*)(ws + 16 * MB);
  u16* vtb  = (u16*)(ws + 40 * MB);
  u16* aout = (u16*)(ws + 48 * MB);
  u16* wTa  = (u16*)(ws + 56 * MB);
  u16* wTq  = (u16*)(ws + 58 * MB);
  u16* wTp  = (u16*)(ws + 64 * MB);
  if (ws_size < 66 * MB) return;

  cast_x<<<2048, 256, 0, stream>>>(x, xb);
  dim3 tcb(32, 8);
  transpose_cast<<<dim3(32, 32), tcb, 0, stream>>>((const float*)d_in[1], wTa, 1024, 1024);
  transpose_cast<<<dim3(96, 32), tcb, 0, stream>>>((const float*)d_in[3], wTq, 1024, 3072);
  transpose_cast<<<dim3(32, 32), tcb, 0, stream>>>((const float*)d_in[5], wTp, 1024, 1024);

  gemm_bt<64, 128, 4, u16><<<dim3(8, 64), 256, 0, stream>>>(xb, wTa, b_attn, hbuf,
                                                            4096, 1024, 1024);
  gemm_bt<128, 128, 2, u16><<<dim3(24, 32), 256, 0, stream>>>(hbuf, wTq, b_qkv, qkvb,
                                                              4096, 3072, 1024);
  transpose_v<<<1024, 256, 0, stream>>>(qkvb, vtb);
  attn_fwd<<<512, 512, 0, stream>>>(qkvb, vtb, aout);
  gemm_bt<64, 128, 4, float><<<dim3(8, 64), 256, 0, stream>>>(aout, wTp, b_proj,
                                                              (float*)d_out,
                                                              4096, 1024, 1024);
}

// Round 9
// 162.109 us; speedup vs baseline: 1.6694x; 1.0497x over previous
//
#include <hip/hip_runtime.h>

typedef unsigned short u16;
typedef unsigned int u32;
typedef __bf16 bf16x8 __attribute__((ext_vector_type(8)));
typedef float f32x4 __attribute__((ext_vector_type(4)));
typedef float f32x16 __attribute__((ext_vector_type(16)));
typedef unsigned uint2v __attribute__((ext_vector_type(2)));

typedef const __attribute__((address_space(1))) void* gcp_t;
typedef __attribute__((address_space(3))) void* lp_t;
#define GLDS16(g, l) __builtin_amdgcn_global_load_lds((gcp_t)(g), (lp_t)(l), 16, 0, 0)

__device__ __forceinline__ u16 f2bf(float f) {
  unsigned int u = __builtin_bit_cast(unsigned int, f);
  u += 0x7fffu + ((u >> 16) & 1u);
  return (u16)(u >> 16);
}
__device__ __forceinline__ u16 bfc(float f) {          // HW cvt (RNE)
  return __builtin_bit_cast(u16, (__bf16)f);
}
__device__ __forceinline__ u32 pkbf(float lo, float hi) {
  return (u32)bfc(lo) | ((u32)bfc(hi) << 16);
}
__device__ __forceinline__ float ex2(float x) {
  return __builtin_amdgcn_exp2f(x);                    // raw v_exp_f32
}

// ---------------------------------------------------------------- prep:
// blocks [0,2048): cast x->bf16 ; [2048,3072): w_attn^T ; [3072,6144): w_qkv^T ;
// [6144,7168): w_proj^T  (transpose+cast [K][N] f32 -> [N][K] bf16)
__global__ __launch_bounds__(256) void prep(const float* __restrict__ x, u16* __restrict__ xb,
                                            const float* __restrict__ wa, u16* __restrict__ wTa,
                                            const float* __restrict__ wq, u16* __restrict__ wTq,
                                            const float* __restrict__ wp, u16* __restrict__ wTp) {
  __shared__ float tile[32][33];
  const int idx = (int)blockIdx.x;
  const int tid = (int)threadIdx.x;
  if (idx < 2048) {
    long i = ((long)idx * 256 + tid) * 8;
    float4 a = *(const float4*)(x + i);
    float4 b = *(const float4*)(x + i + 4);
    union { u16 u[8]; int4 v; } pk;
    pk.u[0] = f2bf(a.x); pk.u[1] = f2bf(a.y); pk.u[2] = f2bf(a.z); pk.u[3] = f2bf(a.w);
    pk.u[4] = f2bf(b.x); pk.u[5] = f2bf(b.y); pk.u[6] = f2bf(b.z); pk.u[7] = f2bf(b.w);
    *(int4*)(xb + i) = pk.v;
    return;
  }
  const float* in; u16* out; int K, N, bx, by;
  if (idx < 3072) {
    int id = idx - 2048; in = wa; out = wTa; K = 1024; N = 1024; bx = id & 31; by = id >> 5;
  } else if (idx < 6144) {
    int id = idx - 3072; in = wq; out = wTq; K = 1024; N = 3072; bx = id % 96; by = id / 96;
  } else {
    int id = idx - 6144; in = wp; out = wTp; K = 1024; N = 1024; bx = id & 31; by = id >> 5;
  }
  const int n0 = bx * 32, k0 = by * 32;
  const int tx = tid & 31, ty = tid >> 5;  // (32,8)
#pragma unroll
  for (int i = 0; i < 4; ++i)
    tile[ty + i * 8][tx] = in[(long)(k0 + ty + i * 8) * N + n0 + tx];
  __syncthreads();
#pragma unroll
  for (int i = 0; i < 4; ++i)
    out[(long)(n0 + ty + i * 8) * K + k0 + tx] = f2bf(tile[tx][ty + i * 8]);
}

// ------------------------------------------- GEMM: C[M][N] = A[M][K] * Bt[N][K]^T + bias
// Double-buffered GLDS16 staging. VSPLIT: blocks with nBase>=2048 (the V third
// of qkv) write vout[bh][d][t] (transposed via in-LDS 128x128) instead of C.
template <int BM, int BN, int WN_WAVES, typename OutT, bool VSPLIT = false>
__global__ __launch_bounds__(256) void gemm_bt(const u16* __restrict__ A,
                                               const u16* __restrict__ Bt,
                                               const float* __restrict__ bias,
                                               OutT* __restrict__ C,
                                               u16* __restrict__ vout,
                                               int M, int N, int K) {
  constexpr int WM = BM / (4 / WN_WAVES);
  constexpr int WN = BN / WN_WAVES;
  constexpr int MF = WM / 16, NF = WN / 16;
  constexpr int STG = 2 * BM * 32 + 2 * BN * 32;   // u16
  constexpr int TRN = VSPLIT ? 128 * 136 : 0;
  constexpr int PSZ = STG > TRN ? STG : TRN;
  __shared__ __align__(16) u16 pool[PSZ];
  u16* lA0 = pool;                  // [2][BM*32]
  u16* lB0 = pool + 2 * BM * 32;    // [2][BN*32]
  const int tid = (int)threadIdx.x;
  const int ln = tid & 63;
  const int w = tid >> 6;
  const int wr = w / WN_WAVES, wc = w % WN_WAVES;
  const int lr = ln & 15, lg = ln >> 4;
  const long mBase = (long)blockIdx.y * BM;
  const long nBase = (long)blockIdx.x * BN;

  f32x4 acc[MF][NF] = {};

  const int r0 = ln >> 2;
  const int c0 = (ln & 3) * 8;

  auto stage = [&](int buf, int k0) {
#pragma unroll
    for (int i = 0; i < BM / 64; ++i) {
      const int br = (i * 4 + w) * 16;
      GLDS16(A + (mBase + br + r0) * K + k0 + c0, lA0 + buf * BM * 32 + br * 32);
    }
#pragma unroll
    for (int i = 0; i < BN / 64; ++i) {
      const int br = (i * 4 + w) * 16;
      GLDS16(Bt + (nBase + br + r0) * K + k0 + c0, lB0 + buf * BN * 32 + br * 32);
    }
  };

  stage(0, 0);
  __syncthreads();
  int cur = 0;
  for (int k0 = 0; k0 < K; k0 += 32) {
    if (k0 + 32 < K) stage(cur ^ 1, k0 + 32);
    bf16x8 af[MF], bfv[NF];
#pragma unroll
    for (int mi = 0; mi < MF; ++mi)
      af[mi] = *(const bf16x8*)&lA0[cur * BM * 32 + (wr * WM + mi * 16 + lr) * 32 + lg * 8];
#pragma unroll
    for (int ni = 0; ni < NF; ++ni)
      bfv[ni] = *(const bf16x8*)&lB0[cur * BN * 32 + (wc * WN + ni * 16 + lr) * 32 + lg * 8];
#pragma unroll
    for (int mi = 0; mi < MF; ++mi)
#pragma unroll
      for (int ni = 0; ni < NF; ++ni)
        acc[mi][ni] = __builtin_amdgcn_mfma_f32_16x16x32_bf16(af[mi], bfv[ni],
                                                              acc[mi][ni], 0, 0, 0);
    __syncthreads();
    cur ^= 1;
  }

  if (VSPLIT && nBase >= 2048) {
    // ---- V third: write bf16(acc+bias) transposed into pool[col][row]
#pragma unroll
    for (int ni = 0; ni < NF; ++ni) {
      const int cl = wc * WN + ni * 16 + lr;
      const float bv = bias[nBase + cl];
#pragma unroll
      for (int mi = 0; mi < MF; ++mi) {
#pragma unroll
        for (int j = 0; j < 4; ++j) {
          const int rl = wr * WM + mi * 16 + lg * 4 + j;
          pool[cl * 136 + rl] = bfc(acc[mi][ni][j] + bv);
        }
      }
    }
    __syncthreads();
    // store: vout[bh][d][t], 2 threads per d-column, 64 t-values each (8x int4)
    const int c = tid >> 1, half = tid & 1;
    const long cglob = nBase + c - 2048;
    const int hh2 = (int)(cglob >> 6), d = (int)(cglob & 63);
    const int bb = (int)(mBase >> 11);
    const int t0 = (int)(mBase & 2047);
    u16* dst = vout + ((long)(bb * 16 + hh2) * 64 + d) * 2048 + t0 + half * 64;
    const u16* srcp = &pool[c * 136 + half * 64];
#pragma unroll
    for (int i = 0; i < 8; ++i)
      *(int4*)(dst + i * 8) = *(const int4*)(srcp + i * 8);
    return;
  }

#pragma unroll
  for (int ni = 0; ni < NF; ++ni) {
    const long col = nBase + wc * WN + ni * 16 + lr;
    const float bv = bias[col];
#pragma unroll
    for (int mi = 0; mi < MF; ++mi) {
      const long row = mBase + wr * WM + mi * 16 + lg * 4;
#pragma unroll
      for (int j = 0; j < 4; ++j) {
        float v = acc[mi][ni][j] + bv;
        if constexpr (sizeof(OutT) == 2) {
          C[(row + j) * N + col] = (OutT)f2bf(v);
        } else {
          C[(row + j) * N + col] = v;
        }
      }
    }
  }
}

// ------------------------------------------- flash attention v7: KV-split 8-wave
// 512 blocks x 512 thr. Swapped-QK 32x32; hoisted swizzle-offsets (buf unrolled
// so all ds_reads are base+imm); lsum via MFMA ones-row; max3 reduce tree;
// permlane32_swap P-pack; setprio around MFMA clusters; LDS-merge of KV halves.
__global__ __launch_bounds__(512, 4) void attn_fwd(const u16* __restrict__ qkv,
                                                   const u16* __restrict__ vt,
                                                   u16* __restrict__ outp) {
  __shared__ __align__(16) u16 smemf[32768];  // 64 KB: [g][buf][K/V][64*64]
  const int tid = (int)threadIdx.x;
  const int ln = tid & 63;
  const int l31 = tid & 31;
  const int hiH = (tid >> 5) & 1;
  const int w = tid >> 6;       // 0..7
  const int g = w >> 2;         // KV-half
  const int qw = w & 3;         // q-block
  const int bid = (int)blockIdx.x;
  const int qt = bid & 15;
  const int bh = bid >> 4;
  const int b = bh >> 4;
  const int hh = bh & 15;

  const float SCALE = 0.125f * 1.44269504088896f;  // 1/sqrt(64) * log2(e)

  // ---- Q fragments (B-operand): col=q=l31, k=d, pre-scaled
  const long qrow = (long)(b * 2048 + qt * 128 + qw * 32 + l31);
  const u16* Qp = qkv + qrow * 3072 + hh * 64;
  bf16x8 qf[4];
#pragma unroll
  for (int ks = 0; ks < 4; ++ks) {
    union { u16 u[8]; int4 i4; bf16x8 v; } in, ov;
    in.i4 = *(const int4*)(Qp + ks * 16 + hiH * 8);
#pragma unroll
    for (int e = 0; e < 8; ++e) {
      float f = __builtin_bit_cast(float, (u32)in.u[e] << 16) * SCALE;
      ov.u[e] = f2bf(f);
    }
    qf[ks] = ov.v;
  }
  bf16x8 onesv;
  {
    union { u16 u[8]; bf16x8 v; } o_;
#pragma unroll
    for (int e = 0; e < 8; ++e) o_.u[e] = 0x3F80;  // bf16 1.0
    onesv = o_.v;
  }

  f32x16 o[2] = {};
  f32x16 lacc = {};
  float mrow = -1e30f;

  const u16* Kbase = qkv + ((long)b * 2048) * 3072 + 1024 + hh * 64;
  const u16* Vbase = vt + (long)bh * 64 * 2048;

  const int sr = ln >> 3;
  const int scm = ln & 7;

  // hoisted swizzled read bases: byte off within tile = t*4096 + l31*128 + ksoff
  const int sw = (l31 & 7) << 4;
  const char* lds0 = (const char*)smemf + g * 32768 + l31 * 128;
  const char* kbse[4];
#pragma unroll
  for (int ks = 0; ks < 4; ++ks) kbse[ks] = lds0 + ((ks * 32 + hiH * 16) ^ sw);

  auto stageKV = [&](int buf, int t) {
    const int kv0 = (g * 16 + t) * 64;
    u16* dstK = smemf + g * 16384 + buf * 8192;
#pragma unroll
    for (int i = 0; i < 2; ++i) {
      const int br = (i * 4 + qw) * 8;
      const int r = br + sr;
      const int cs = scm ^ (r & 7);
      GLDS16(Kbase + (long)(kv0 + r) * 3072 + cs * 8, dstK + br * 64);
      GLDS16(Vbase + (long)r * 2048 + kv0 + cs * 8, dstK + 4096 + br * 64);
    }
  };

  stageKV(0, 0);
  __syncthreads();

  auto tile = [&](int buf, int kt) {
    if (kt + 1 < 16) stageKV(buf ^ 1, kt + 1);
    const int boff = buf * 16384;  // bytes

    // ---- QK^T (swapped)
    f32x16 st[2] = {};
    __builtin_amdgcn_s_setprio(1);
#pragma unroll
    for (int t = 0; t < 2; ++t)
#pragma unroll
      for (int ks = 0; ks < 4; ++ks) {
        const bf16x8 kf = *(const bf16x8*)(kbse[ks] + boff + t * 4096);
        st[t] = __builtin_amdgcn_mfma_f32_32x32x16_bf16(kf, qf[ks], st[t], 0, 0, 0);
      }
    __builtin_amdgcn_s_setprio(0);

    // ---- row max via max3 tree (17 ops)
    float mv[32];
#pragma unroll
    for (int t = 0; t < 2; ++t)
#pragma unroll
      for (int r = 0; r < 16; ++r) mv[t * 16 + r] = st[t][r];
    float m1[11];
#pragma unroll
    for (int i = 0; i < 10; ++i)
      m1[i] = fmaxf(fmaxf(mv[3 * i], mv[3 * i + 1]), mv[3 * i + 2]);
    m1[10] = fmaxf(mv[30], mv[31]);
    float m2[4];
    m2[0] = fmaxf(fmaxf(m1[0], m1[1]), m1[2]);
    m2[1] = fmaxf(fmaxf(m1[3], m1[4]), m1[5]);
    m2[2] = fmaxf(fmaxf(m1[6], m1[7]), m1[8]);
    m2[3] = fmaxf(m1[9], m1[10]);
    float mx = fmaxf(fmaxf(fmaxf(m2[0], m2[1]), m2[2]), m2[3]);
    mx = fmaxf(mx, __shfl_xor(mx, 32));

    if (!__all(mx <= mrow + 8.0f)) {
      const float mnew = fmaxf(mrow, mx);
      const float sf = ex2(mrow - mnew);
      mrow = mnew;
      lacc[0] *= sf;
      o[0] *= sf;
      o[1] *= sf;
    }

#pragma unroll
    for (int t = 0; t < 2; ++t)
#pragma unroll
      for (int r = 0; r < 16; ++r) st[t][r] = ex2(st[t][r] - mrow);

    // ---- pack P -> PV B-frags via permlane32_swap
    bf16x8 pa[4];
#pragma unroll
    for (int t = 0; t < 2; ++t)
#pragma unroll
      for (int gg = 0; gg < 2; ++gg) {
        const int bse = gg * 8;
        u32 A = pkbf(st[t][bse + 0], st[t][bse + 1]);
        u32 B = pkbf(st[t][bse + 2], st[t][bse + 3]);
        u32 C = pkbf(st[t][bse + 4], st[t][bse + 5]);
        u32 D = pkbf(st[t][bse + 6], st[t][bse + 7]);
        union { u32 wv[4]; bf16x8 v; } u;
#if __has_builtin(__builtin_amdgcn_permlane32_swap)
        uint2v r0 = __builtin_amdgcn_permlane32_swap(A, C, false, false);
        uint2v r1 = __builtin_amdgcn_permlane32_swap(B, D, false, false);
        u.wv[0] = r0[0]; u.wv[1] = r1[0]; u.wv[2] = r0[1]; u.wv[3] = r1[1];
#else
        const u32 sA = __shfl_xor((int)A, 32);
        const u32 sB = __shfl_xor((int)B, 32);
        const u32 sC = __shfl_xor((int)C, 32);
        const u32 sD = __shfl_xor((int)D, 32);
        u.wv[0] = hiH ? sC : A;
        u.wv[1] = hiH ? sD : B;
        u.wv[2] = hiH ? C : sA;
        u.wv[3] = hiH ? D : sB;
#endif
        pa[t * 2 + gg] = u.v;
      }

    // ---- lsum (ones-row MFMA) + PV
    __builtin_amdgcn_s_setprio(1);
#pragma unroll
    for (int ks2 = 0; ks2 < 4; ++ks2)
      lacc = __builtin_amdgcn_mfma_f32_32x32x16_bf16(onesv, pa[ks2], lacc, 0, 0, 0);
#pragma unroll
    for (int dt = 0; dt < 2; ++dt)
#pragma unroll
      for (int ks2 = 0; ks2 < 4; ++ks2) {
        const bf16x8 vf = *(const bf16x8*)(kbse[ks2] + boff + 8192 + dt * 4096);
        o[dt] = __builtin_amdgcn_mfma_f32_32x32x16_bf16(vf, pa[ks2], o[dt], 0, 0, 0);
      }
    __builtin_amdgcn_s_setprio(0);
    __syncthreads();
  };

  for (int k8 = 0; k8 < 8; ++k8) {
    tile(0, k8 * 2);
    tile(1, k8 * 2 + 1);
  }

  // ---- merge the two KV-half partials, normalize, store
  const float lsum_tot = lacc[0];
  float* PO = (float*)smemf;                       // 32 KB
  float* MLf = (float*)((char*)smemf + 32768);     // 4 KB

  if (g == 1) {
    float* dst = PO + (w - 4) * 2048 + ln * 32;
#pragma unroll
    for (int dt = 0; dt < 2; ++dt)
#pragma unroll
      for (int q4 = 0; q4 < 4; ++q4) {
        f32x4 c;
#pragma unroll
        for (int j = 0; j < 4; ++j) c[j] = o[dt][q4 * 4 + j];
        *(f32x4*)(dst + dt * 16 + q4 * 4) = c;
      }
    MLf[(w - 4) * 128 + ln * 2] = mrow;
    MLf[(w - 4) * 128 + ln * 2 + 1] = lsum_tot;
  }
  __syncthreads();
  if (g == 0) {
    const float m1v = MLf[w * 128 + ln * 2];
    const float l1 = MLf[w * 128 + ln * 2 + 1];
    const float* src = PO + w * 2048 + ln * 32;
    const float m = fmaxf(mrow, m1v);
    const float a0 = ex2(mrow - m);
    const float a1 = ex2(m1v - m);
    const float linv = 1.0f / (lsum_tot * a0 + l1 * a1);
    u16* T = (u16*)((char*)smemf + 36864) + w * (32 * 72);
#pragma unroll
    for (int dt = 0; dt < 2; ++dt) {
      float o1[16];
#pragma unroll
      for (int q4 = 0; q4 < 4; ++q4) {
        const f32x4 c = *(const f32x4*)(src + dt * 16 + q4 * 4);
#pragma unroll
        for (int j = 0; j < 4; ++j) o1[q4 * 4 + j] = c[j];
      }
#pragma unroll
      for (int r = 0; r < 16; ++r) {
        const float v = (o[dt][r] * a0 + o1[r] * a1) * linv;
        const int d = (r & 3) + 8 * (r >> 2) + 4 * hiH + dt * 32;
        T[l31 * 72 + d] = bfc(v);
      }
    }
    asm volatile("s_waitcnt lgkmcnt(0)" ::: "memory");
    __builtin_amdgcn_sched_barrier(0);
    const int rr = ln >> 1;
    const int c0 = (ln & 1) * 32;
    u16* orow = outp + ((long)(b * 2048 + qt * 128 + w * 32 + rr)) * 1024 + hh * 64 + c0;
#pragma unroll
    for (int i = 0; i < 4; ++i)
      *(int4*)(orow + i * 8) = *(const int4*)&T[rr * 72 + c0 + i * 8];
  }
}

// ----------------------------------------------------------------------------
extern "C" void kernel_launch(void* const* d_in, const int* in_sizes, int n_in,
                              void* d_out, int out_size, void* d_ws, size_t ws_size,
                              hipStream_t stream) {
  (void)in_sizes; (void)n_in; (void)out_size;
  const float* x = (const float*)d_in[0];
  const float* b_attn = (const float*)d_in[2];
  const float* b_qkv = (const float*)d_in[4];
  const float* b_proj = (const float*)d_in[6];

  char* ws = (char*)d_ws;
  const size_t MB = 1024 * 1024;
  u16* xb   = (u16*)(ws + 0 * MB);
  u16* hbuf = (u16*)(ws + 8 * MB);
  u16* qkvb = (u16*)(ws + 16 * MB);
  u16* vtb  = (u16*)(ws + 40 * MB);
  u16* aout = (u16*)(ws + 48 * MB);
  u16* wTa  = (u16*)(ws + 56 * MB);
  u16* wTq  = (u16*)(ws + 58 * MB);
  u16* wTp  = (u16*)(ws + 64 * MB);
  if (ws_size < 66 * MB) return;

  prep<<<7168, 256, 0, stream>>>(x, xb, (const float*)d_in[1], wTa,
                                 (const float*)d_in[3], wTq,
                                 (const float*)d_in[5], wTp);

  gemm_bt<64, 128, 4, u16><<<dim3(8, 64), 256, 0, stream>>>(
      xb, wTa, b_attn, hbuf, nullptr, 4096, 1024, 1024);
  // qkv GEMM: Q,K thirds -> qkvb; V third -> vtb (transposed in epilogue)
  gemm_bt<128, 128, 2, u16, true><<<dim3(24, 32), 256, 0, stream>>>(
      hbuf, wTq, b_qkv, qkvb, vtb, 4096, 3072, 1024);
  attn_fwd<<<512, 512, 0, stream>>>(qkvb, vtb, aout);
  gemm_bt<64, 128, 4, float><<<dim3(8, 64), 256, 0, stream>>>(
      aout, wTp, b_proj, (float*)d_out, nullptr, 4096, 1024, 1024);
}

// Round 10
// 151.319 us; speedup vs baseline: 1.7885x; 1.0713x over previous
//
#include <hip/hip_runtime.h>

typedef unsigned short u16;
typedef unsigned int u32;
typedef __bf16 bf16x8 __attribute__((ext_vector_type(8)));
typedef float f32x4 __attribute__((ext_vector_type(4)));
typedef float f32x16 __attribute__((ext_vector_type(16)));
typedef unsigned uint2v __attribute__((ext_vector_type(2)));

typedef const __attribute__((address_space(1))) void* gcp_t;
typedef __attribute__((address_space(3))) void* lp_t;
#define GLDS16(g, l) __builtin_amdgcn_global_load_lds((gcp_t)(g), (lp_t)(l), 16, 0, 0)

__device__ __forceinline__ u16 f2bf(float f) {
  unsigned int u = __builtin_bit_cast(unsigned int, f);
  u += 0x7fffu + ((u >> 16) & 1u);
  return (u16)(u >> 16);
}
__device__ __forceinline__ u16 bfc(float f) {          // HW cvt (RNE)
  return __builtin_bit_cast(u16, (__bf16)f);
}
__device__ __forceinline__ u32 pkbf(float lo, float hi) {
  return (u32)bfc(lo) | ((u32)bfc(hi) << 16);
}
__device__ __forceinline__ float ex2(float x) {
  return __builtin_amdgcn_exp2f(x);                    // raw v_exp_f32
}

// ---------------------------------------------------------------- prep:
// blocks [0,2048): cast x->bf16 ; [2048,3072): w_attn^T ; [3072,6144): w_qkv^T ;
// [6144,7168): w_proj^T  (transpose+cast [K][N] f32 -> [N][K] bf16)
__global__ __launch_bounds__(256) void prep(const float* __restrict__ x, u16* __restrict__ xb,
                                            const float* __restrict__ wa, u16* __restrict__ wTa,
                                            const float* __restrict__ wq, u16* __restrict__ wTq,
                                            const float* __restrict__ wp, u16* __restrict__ wTp) {
  __shared__ float tile[32][33];
  const int idx = (int)blockIdx.x;
  const int tid = (int)threadIdx.x;
  if (idx < 2048) {
    long i = ((long)idx * 256 + tid) * 8;
    float4 a = *(const float4*)(x + i);
    float4 b = *(const float4*)(x + i + 4);
    union { u16 u[8]; int4 v; } pk;
    pk.u[0] = f2bf(a.x); pk.u[1] = f2bf(a.y); pk.u[2] = f2bf(a.z); pk.u[3] = f2bf(a.w);
    pk.u[4] = f2bf(b.x); pk.u[5] = f2bf(b.y); pk.u[6] = f2bf(b.z); pk.u[7] = f2bf(b.w);
    *(int4*)(xb + i) = pk.v;
    return;
  }
  const float* in; u16* out; int K, N, bx, by;
  if (idx < 3072) {
    int id = idx - 2048; in = wa; out = wTa; K = 1024; N = 1024; bx = id & 31; by = id >> 5;
  } else if (idx < 6144) {
    int id = idx - 3072; in = wq; out = wTq; K = 1024; N = 3072; bx = id % 96; by = id / 96;
  } else {
    int id = idx - 6144; in = wp; out = wTp; K = 1024; N = 1024; bx = id & 31; by = id >> 5;
  }
  const int n0 = bx * 32, k0 = by * 32;
  const int tx = tid & 31, ty = tid >> 5;  // (32,8)
#pragma unroll
  for (int i = 0; i < 4; ++i)
    tile[ty + i * 8][tx] = in[(long)(k0 + ty + i * 8) * N + n0 + tx];
  __syncthreads();
#pragma unroll
  for (int i = 0; i < 4; ++i)
    out[(long)(n0 + ty + i * 8) * K + k0 + tx] = f2bf(tile[tx][ty + i * 8]);
}

// ------------------------------------------- GEMM: C[M][N] = A[M][K] * Bt[N][K]^T + bias
// Double-buffered GLDS16 staging; XCD-aware bijective block swizzle (grid%8==0).
// VSPLIT: blocks with nBase>=2048 (V third of qkv) write vout[bh][d][t].
template <int BM, int BN, int WN_WAVES, typename OutT, bool VSPLIT = false>
__global__ __launch_bounds__(256) void gemm_bt(const u16* __restrict__ A,
                                               const u16* __restrict__ Bt,
                                               const float* __restrict__ bias,
                                               OutT* __restrict__ C,
                                               u16* __restrict__ vout,
                                               int M, int N, int K) {
  constexpr int WM = BM / (4 / WN_WAVES);
  constexpr int WN = BN / WN_WAVES;
  constexpr int MF = WM / 16, NF = WN / 16;
  constexpr int STG = 2 * BM * 32 + 2 * BN * 32;   // u16
  constexpr int TRN = VSPLIT ? 128 * 136 : 0;
  constexpr int PSZ = STG > TRN ? STG : TRN;
  __shared__ __align__(16) u16 pool[PSZ];
  u16* lA0 = pool;                  // [2][BM*32]
  u16* lB0 = pool + 2 * BM * 32;    // [2][BN*32]
  const int tid = (int)threadIdx.x;
  const int ln = tid & 63;
  const int w = tid >> 6;
  const int wr = w / WN_WAVES, wc = w % WN_WAVES;
  const int lr = ln & 15, lg = ln >> 4;

  // XCD swizzle: contiguous logical-block chunk per XCD
  const int nwg = (int)(gridDim.x * gridDim.y);
  const int lin = (int)(blockIdx.y * gridDim.x + blockIdx.x);
  const int cpx = nwg >> 3;
  const int swzb = (lin & 7) * cpx + (lin >> 3);
  const int bx = swzb % (int)gridDim.x;
  const int by = swzb / (int)gridDim.x;
  const long mBase = (long)by * BM;
  const long nBase = (long)bx * BN;

  f32x4 acc[MF][NF] = {};

  const int r0 = ln >> 2;
  const int c0 = (ln & 3) * 8;

  auto stage = [&](int buf, int k0) {
#pragma unroll
    for (int i = 0; i < BM / 64; ++i) {
      const int br = (i * 4 + w) * 16;
      GLDS16(A + (mBase + br + r0) * K + k0 + c0, lA0 + buf * BM * 32 + br * 32);
    }
#pragma unroll
    for (int i = 0; i < BN / 64; ++i) {
      const int br = (i * 4 + w) * 16;
      GLDS16(Bt + (nBase + br + r0) * K + k0 + c0, lB0 + buf * BN * 32 + br * 32);
    }
  };

  stage(0, 0);
  __syncthreads();
  int cur = 0;
  for (int k0 = 0; k0 < K; k0 += 32) {
    if (k0 + 32 < K) stage(cur ^ 1, k0 + 32);
    bf16x8 af[MF], bfv[NF];
#pragma unroll
    for (int mi = 0; mi < MF; ++mi)
      af[mi] = *(const bf16x8*)&lA0[cur * BM * 32 + (wr * WM + mi * 16 + lr) * 32 + lg * 8];
#pragma unroll
    for (int ni = 0; ni < NF; ++ni)
      bfv[ni] = *(const bf16x8*)&lB0[cur * BN * 32 + (wc * WN + ni * 16 + lr) * 32 + lg * 8];
#pragma unroll
    for (int mi = 0; mi < MF; ++mi)
#pragma unroll
      for (int ni = 0; ni < NF; ++ni)
        acc[mi][ni] = __builtin_amdgcn_mfma_f32_16x16x32_bf16(af[mi], bfv[ni],
                                                              acc[mi][ni], 0, 0, 0);
    __syncthreads();
    cur ^= 1;
  }

  if (VSPLIT && nBase >= 2048) {
    // ---- V third: write bf16(acc+bias) transposed into pool[col][row]
#pragma unroll
    for (int ni = 0; ni < NF; ++ni) {
      const int cl = wc * WN + ni * 16 + lr;
      const float bv = bias[nBase + cl];
#pragma unroll
      for (int mi = 0; mi < MF; ++mi) {
#pragma unroll
        for (int j = 0; j < 4; ++j) {
          const int rl = wr * WM + mi * 16 + lg * 4 + j;
          pool[cl * 136 + rl] = bfc(acc[mi][ni][j] + bv);
        }
      }
    }
    __syncthreads();
    // store: vout[bh][d][t], 2 threads per d-column, 64 t-values each (8x int4)
    const int c = tid >> 1, half = tid & 1;
    const long cglob = nBase + c - 2048;
    const int hh2 = (int)(cglob >> 6), d = (int)(cglob & 63);
    const int bb = (int)(mBase >> 11);
    const int t0 = (int)(mBase & 2047);
    u16* dst = vout + ((long)(bb * 16 + hh2) * 64 + d) * 2048 + t0 + half * 64;
    const u16* srcp = &pool[c * 136 + half * 64];
#pragma unroll
    for (int i = 0; i < 8; ++i)
      *(int4*)(dst + i * 8) = *(const int4*)(srcp + i * 8);
    return;
  }

#pragma unroll
  for (int ni = 0; ni < NF; ++ni) {
    const long col = nBase + wc * WN + ni * 16 + lr;
    const float bv = bias[col];
#pragma unroll
    for (int mi = 0; mi < MF; ++mi) {
      const long row = mBase + wr * WM + mi * 16 + lg * 4;
#pragma unroll
      for (int j = 0; j < 4; ++j) {
        float v = acc[mi][ni][j] + bv;
        if constexpr (sizeof(OutT) == 2) {
          C[(row + j) * N + col] = (OutT)f2bf(v);
        } else {
          C[(row + j) * N + col] = v;
        }
      }
    }
  }
}

// ------------------------------------------- flash attention v8: KV-split 8-wave
// 512 blocks x 512 thr, XCD-swizzled (4 bh per XCD -> K/V L2-resident).
// Swapped-QK 32x32; hoisted swizzle bases (all ds_reads base+imm); VALU
// pairwise lsum tree; max3 reduce; permlane32_swap P-pack; LDS-merge.
__global__ __launch_bounds__(512, 4) void attn_fwd(const u16* __restrict__ qkv,
                                                   const u16* __restrict__ vt,
                                                   u16* __restrict__ outp) {
  __shared__ __align__(16) u16 smemf[32768];  // 64 KB: [g][buf][K/V][64*64]
  const int tid = (int)threadIdx.x;
  const int ln = tid & 63;
  const int l31 = tid & 31;
  const int hiH = (tid >> 5) & 1;
  const int w = tid >> 6;       // 0..7
  const int g = w >> 2;         // KV-half
  const int qw = w & 3;         // q-block
  const int bid0 = (int)blockIdx.x;
  const int bid = ((bid0 & 7) << 6) | (bid0 >> 3);   // XCD swizzle (512 = 8*64)
  const int qt = bid & 15;
  const int bh = bid >> 4;
  const int b = bh >> 4;
  const int hh = bh & 15;

  const float SCALE = 0.125f * 1.44269504088896f;  // 1/sqrt(64) * log2(e)

  // ---- Q fragments (B-operand): col=q=l31, k=d, pre-scaled
  const long qrow = (long)(b * 2048 + qt * 128 + qw * 32 + l31);
  const u16* Qp = qkv + qrow * 3072 + hh * 64;
  bf16x8 qf[4];
#pragma unroll
  for (int ks = 0; ks < 4; ++ks) {
    union { u16 u[8]; int4 i4; bf16x8 v; } in, ov;
    in.i4 = *(const int4*)(Qp + ks * 16 + hiH * 8);
#pragma unroll
    for (int e = 0; e < 8; ++e) {
      float f = __builtin_bit_cast(float, (u32)in.u[e] << 16) * SCALE;
      ov.u[e] = f2bf(f);
    }
    qf[ks] = ov.v;
  }

  f32x16 o[2] = {};
  float mrow = -1e30f, lsum = 0.f;

  const u16* Kbase = qkv + ((long)b * 2048) * 3072 + 1024 + hh * 64;
  const u16* Vbase = vt + (long)bh * 64 * 2048;

  const int sr = ln >> 3;
  const int scm = ln & 7;

  // hoisted swizzled read bases: byte off within tile = t*4096 + l31*128 + ksoff
  const int sw = (l31 & 7) << 4;
  const char* lds0 = (const char*)smemf + g * 32768 + l31 * 128;
  const char* kbse[4];
#pragma unroll
  for (int ks = 0; ks < 4; ++ks) kbse[ks] = lds0 + ((ks * 32 + hiH * 16) ^ sw);

  auto stageKV = [&](int buf, int t) {
    const int kv0 = (g * 16 + t) * 64;
    u16* dstK = smemf + g * 16384 + buf * 8192;
#pragma unroll
    for (int i = 0; i < 2; ++i) {
      const int br = (i * 4 + qw) * 8;
      const int r = br + sr;
      const int cs = scm ^ (r & 7);
      GLDS16(Kbase + (long)(kv0 + r) * 3072 + cs * 8, dstK + br * 64);
      GLDS16(Vbase + (long)r * 2048 + kv0 + cs * 8, dstK + 4096 + br * 64);
    }
  };

  stageKV(0, 0);
  __syncthreads();

  auto tile = [&](int buf, int kt) {
    if (kt + 1 < 16) stageKV(buf ^ 1, kt + 1);
    const int boff = buf * 16384;  // bytes

    // ---- QK^T (swapped)
    f32x16 st[2] = {};
#pragma unroll
    for (int t = 0; t < 2; ++t)
#pragma unroll
      for (int ks = 0; ks < 4; ++ks) {
        const bf16x8 kf = *(const bf16x8*)(kbse[ks] + boff + t * 4096);
        st[t] = __builtin_amdgcn_mfma_f32_32x32x16_bf16(kf, qf[ks], st[t], 0, 0, 0);
      }

    // ---- row max via max3 tree
    float mv[32];
#pragma unroll
    for (int t = 0; t < 2; ++t)
#pragma unroll
      for (int r = 0; r < 16; ++r) mv[t * 16 + r] = st[t][r];
    float m1[11];
#pragma unroll
    for (int i = 0; i < 10; ++i)
      m1[i] = fmaxf(fmaxf(mv[3 * i], mv[3 * i + 1]), mv[3 * i + 2]);
    m1[10] = fmaxf(mv[30], mv[31]);
    float m2[4];
    m2[0] = fmaxf(fmaxf(m1[0], m1[1]), m1[2]);
    m2[1] = fmaxf(fmaxf(m1[3], m1[4]), m1[5]);
    m2[2] = fmaxf(fmaxf(m1[6], m1[7]), m1[8]);
    m2[3] = fmaxf(m1[9], m1[10]);
    float mx = fmaxf(fmaxf(fmaxf(m2[0], m2[1]), m2[2]), m2[3]);
    mx = fmaxf(mx, __shfl_xor(mx, 32));

    if (!__all(mx <= mrow + 8.0f)) {
      const float mnew = fmaxf(mrow, mx);
      const float sf = ex2(mrow - mnew);
      mrow = mnew;
      lsum *= sf;
      o[0] *= sf;
      o[1] *= sf;
    }

#pragma unroll
    for (int t = 0; t < 2; ++t)
#pragma unroll
      for (int r = 0; r < 16; ++r) st[t][r] = ex2(st[t][r] - mrow);

    // ---- lsum: VALU pairwise tree (31 adds), per-lane partial
    float ts[16];
#pragma unroll
    for (int r = 0; r < 16; ++r) ts[r] = st[0][r] + st[1][r];
#pragma unroll
    for (int s = 8; s > 0; s >>= 1)
#pragma unroll
      for (int r = 0; r < 8; ++r)
        if (r < s) ts[r] += ts[r + s];
    lsum += ts[0];

    // ---- pack P -> PV B-frags via permlane32_swap
    bf16x8 pa[4];
#pragma unroll
    for (int t = 0; t < 2; ++t)
#pragma unroll
      for (int gg = 0; gg < 2; ++gg) {
        const int bse = gg * 8;
        u32 A = pkbf(st[t][bse + 0], st[t][bse + 1]);
        u32 B = pkbf(st[t][bse + 2], st[t][bse + 3]);
        u32 C = pkbf(st[t][bse + 4], st[t][bse + 5]);
        u32 D = pkbf(st[t][bse + 6], st[t][bse + 7]);
        union { u32 wv[4]; bf16x8 v; } u;
#if __has_builtin(__builtin_amdgcn_permlane32_swap)
        uint2v r0 = __builtin_amdgcn_permlane32_swap(A, C, false, false);
        uint2v r1 = __builtin_amdgcn_permlane32_swap(B, D, false, false);
        u.wv[0] = r0[0]; u.wv[1] = r1[0]; u.wv[2] = r0[1]; u.wv[3] = r1[1];
#else
        const u32 sA = __shfl_xor((int)A, 32);
        const u32 sB = __shfl_xor((int)B, 32);
        const u32 sC = __shfl_xor((int)C, 32);
        const u32 sD = __shfl_xor((int)D, 32);
        u.wv[0] = hiH ? sC : A;
        u.wv[1] = hiH ? sD : B;
        u.wv[2] = hiH ? C : sA;
        u.wv[3] = hiH ? D : sB;
#endif
        pa[t * 2 + gg] = u.v;
      }

    // ---- PV: O^T[d][q] += Vt[d][kv] * P^T[kv][q]
#pragma unroll
    for (int dt = 0; dt < 2; ++dt)
#pragma unroll
      for (int ks2 = 0; ks2 < 4; ++ks2) {
        const bf16x8 vf = *(const bf16x8*)(kbse[ks2] + boff + 8192 + dt * 4096);
        o[dt] = __builtin_amdgcn_mfma_f32_32x32x16_bf16(vf, pa[ks2], o[dt], 0, 0, 0);
      }
    __syncthreads();
  };

  for (int k8 = 0; k8 < 8; ++k8) {
    tile(0, k8 * 2);
    tile(1, k8 * 2 + 1);
  }

  // ---- merge the two KV-half partials, normalize, store
  const float lsum_tot = lsum + __shfl_xor(lsum, 32);
  float* PO = (float*)smemf;                       // 32 KB
  float* MLf = (float*)((char*)smemf + 32768);     // 4 KB

  if (g == 1) {
    float* dst = PO + (w - 4) * 2048 + ln * 32;
#pragma unroll
    for (int dt = 0; dt < 2; ++dt)
#pragma unroll
      for (int q4 = 0; q4 < 4; ++q4) {
        f32x4 c;
#pragma unroll
        for (int j = 0; j < 4; ++j) c[j] = o[dt][q4 * 4 + j];
        *(f32x4*)(dst + dt * 16 + q4 * 4) = c;
      }
    MLf[(w - 4) * 128 + ln * 2] = mrow;
    MLf[(w - 4) * 128 + ln * 2 + 1] = lsum_tot;
  }
  __syncthreads();
  if (g == 0) {
    const float m1v = MLf[w * 128 + ln * 2];
    const float l1 = MLf[w * 128 + ln * 2 + 1];
    const float* src = PO + w * 2048 + ln * 32;
    const float m = fmaxf(mrow, m1v);
    const float a0 = ex2(mrow - m);
    const float a1 = ex2(m1v - m);
    const float linv = 1.0f / (lsum_tot * a0 + l1 * a1);
    u16* T = (u16*)((char*)smemf + 36864) + w * (32 * 72);
#pragma unroll
    for (int dt = 0; dt < 2; ++dt) {
      float o1[16];
#pragma unroll
      for (int q4 = 0; q4 < 4; ++q4) {
        const f32x4 c = *(const f32x4*)(src + dt * 16 + q4 * 4);
#pragma unroll
        for (int j = 0; j < 4; ++j) o1[q4 * 4 + j] = c[j];
      }
#pragma unroll
      for (int r = 0; r < 16; ++r) {
        const float v = (o[dt][r] * a0 + o1[r] * a1) * linv;
        const int d = (r & 3) + 8 * (r >> 2) + 4 * hiH + dt * 32;
        T[l31 * 72 + d] = bfc(v);
      }
    }
    asm volatile("s_waitcnt lgkmcnt(0)" ::: "memory");
    __builtin_amdgcn_sched_barrier(0);
    const int rr = ln >> 1;
    const int c0 = (ln & 1) * 32;
    u16* orow = outp + ((long)(b * 2048 + qt * 128 + w * 32 + rr)) * 1024 + hh * 64 + c0;
#pragma unroll
    for (int i = 0; i < 4; ++i)
      *(int4*)(orow + i * 8) = *(const int4*)&T[rr * 72 + c0 + i * 8];
  }
}

// ----------------------------------------------------------------------------
extern "C" void kernel_launch(void* const* d_in, const int* in_sizes, int n_in,
                              void* d_out, int out_size, void* d_ws, size_t ws_size,
                              hipStream_t stream) {
  (void)in_sizes; (void)n_in; (void)out_size;
  const float* x = (const float*)d_in[0];
  const float* b_attn = (const float*)d_in[2];
  const float* b_qkv = (const float*)d_in[4];
  const float* b_proj = (const float*)d_in[6];

  char* ws = (char*)d_ws;
  const size_t MB = 1024 * 1024;
  u16* xb   = (u16*)(ws + 0 * MB);
  u16* hbuf = (u16*)(ws + 8 * MB);
  u16* qkvb = (u16*)(ws + 16 * MB);
  u16* vtb  = (u16*)(ws + 40 * MB);
  u16* aout = (u16*)(ws + 48 * MB);
  u16* wTa  = (u16*)(ws + 56 * MB);
  u16* wTq  = (u16*)(ws + 58 * MB);
  u16* wTp  = (u16*)(ws + 64 * MB);
  if (ws_size < 66 * MB) return;

  prep<<<7168, 256, 0, stream>>>(x, xb, (const float*)d_in[1], wTa,
                                 (const float*)d_in[3], wTq,
                                 (const float*)d_in[5], wTp);

  gemm_bt<64, 128, 4, u16><<<dim3(8, 64), 256, 0, stream>>>(
      xb, wTa, b_attn, hbuf, nullptr, 4096, 1024, 1024);
  // qkv GEMM: Q,K thirds -> qkvb; V third -> vtb (transposed in epilogue)
  gemm_bt<128, 128, 2, u16, true><<<dim3(24, 32), 256, 0, stream>>>(
      hbuf, wTq, b_qkv, qkvb, vtb, 4096, 3072, 1024);
  attn_fwd<<<512, 512, 0, stream>>>(qkvb, vtb, aout);
  gemm_bt<64, 128, 4, float><<<dim3(8, 64), 256, 0, stream>>>(
      aout, wTp, b_proj, (float*)d_out, nullptr, 4096, 1024, 1024);
}

// Round 11
// 151.302 us; speedup vs baseline: 1.7887x; 1.0001x over previous
//
#include <hip/hip_runtime.h>

typedef unsigned short u16;
typedef unsigned int u32;
typedef __bf16 bf16x8 __attribute__((ext_vector_type(8)));
typedef float f32x4 __attribute__((ext_vector_type(4)));
typedef float f32x16 __attribute__((ext_vector_type(16)));
typedef unsigned uint2v __attribute__((ext_vector_type(2)));

typedef const __attribute__((address_space(1))) void* gcp_t;
typedef __attribute__((address_space(3))) void* lp_t;
#define GLDS16(g, l) __builtin_amdgcn_global_load_lds((gcp_t)(g), (lp_t)(l), 16, 0, 0)

__device__ __forceinline__ u16 f2bf(float f) {
  unsigned int u = __builtin_bit_cast(unsigned int, f);
  u += 0x7fffu + ((u >> 16) & 1u);
  return (u16)(u >> 16);
}
__device__ __forceinline__ u16 bfc(float f) {          // HW cvt (RNE)
  return __builtin_bit_cast(u16, (__bf16)f);
}
__device__ __forceinline__ u32 pkbf(float lo, float hi) {
  return (u32)bfc(lo) | ((u32)bfc(hi) << 16);
}
__device__ __forceinline__ float ex2(float x) {
  return __builtin_amdgcn_exp2f(x);                    // raw v_exp_f32
}

// ---------------------------------------------------------------- prep:
// blocks [0,2048): cast x->bf16 ; [2048,3072): w_attn^T ; [3072,6144): w_qkv^T ;
// [6144,7168): w_proj^T  (transpose+cast [K][N] f32 -> [N][K] bf16)
__global__ __launch_bounds__(256) void prep(const float* __restrict__ x, u16* __restrict__ xb,
                                            const float* __restrict__ wa, u16* __restrict__ wTa,
                                            const float* __restrict__ wq, u16* __restrict__ wTq,
                                            const float* __restrict__ wp, u16* __restrict__ wTp) {
  __shared__ float tile[32][33];
  const int idx = (int)blockIdx.x;
  const int tid = (int)threadIdx.x;
  if (idx < 2048) {
    long i = ((long)idx * 256 + tid) * 8;
    float4 a = *(const float4*)(x + i);
    float4 b = *(const float4*)(x + i + 4);
    union { u16 u[8]; int4 v; } pk;
    pk.u[0] = f2bf(a.x); pk.u[1] = f2bf(a.y); pk.u[2] = f2bf(a.z); pk.u[3] = f2bf(a.w);
    pk.u[4] = f2bf(b.x); pk.u[5] = f2bf(b.y); pk.u[6] = f2bf(b.z); pk.u[7] = f2bf(b.w);
    *(int4*)(xb + i) = pk.v;
    return;
  }
  const float* in; u16* out; int K, N, bx, by;
  if (idx < 3072) {
    int id = idx - 2048; in = wa; out = wTa; K = 1024; N = 1024; bx = id & 31; by = id >> 5;
  } else if (idx < 6144) {
    int id = idx - 3072; in = wq; out = wTq; K = 1024; N = 3072; bx = id % 96; by = id / 96;
  } else {
    int id = idx - 6144; in = wp; out = wTp; K = 1024; N = 1024; bx = id & 31; by = id >> 5;
  }
  const int n0 = bx * 32, k0 = by * 32;
  const int tx = tid & 31, ty = tid >> 5;  // (32,8)
#pragma unroll
  for (int i = 0; i < 4; ++i)
    tile[ty + i * 8][tx] = in[(long)(k0 + ty + i * 8) * N + n0 + tx];
  __syncthreads();
#pragma unroll
  for (int i = 0; i < 4; ++i)
    out[(long)(n0 + ty + i * 8) * K + k0 + tx] = f2bf(tile[tx][ty + i * 8]);
}

// ------------------------------------------- GEMM: C[M][N] = A[M][K] * Bt[N][K]^T + bias
// Double-buffered GLDS16 staging; XCD-aware bijective block swizzle (grid%8==0).
// VSPLIT: blocks with nBase>=2048 (V third of qkv) write vout[bh][d][t].
template <int BM, int BN, int WN_WAVES, typename OutT, bool VSPLIT = false>
__global__ __launch_bounds__(256) void gemm_bt(const u16* __restrict__ A,
                                               const u16* __restrict__ Bt,
                                               const float* __restrict__ bias,
                                               OutT* __restrict__ C,
                                               u16* __restrict__ vout,
                                               int M, int N, int K) {
  constexpr int WM = BM / (4 / WN_WAVES);
  constexpr int WN = BN / WN_WAVES;
  constexpr int MF = WM / 16, NF = WN / 16;
  constexpr int STG = 2 * BM * 32 + 2 * BN * 32;   // u16
  constexpr int TRN = VSPLIT ? 128 * 136 : 0;
  constexpr int PSZ = STG > TRN ? STG : TRN;
  __shared__ __align__(16) u16 pool[PSZ];
  u16* lA0 = pool;                  // [2][BM*32]
  u16* lB0 = pool + 2 * BM * 32;    // [2][BN*32]
  const int tid = (int)threadIdx.x;
  const int ln = tid & 63;
  const int w = tid >> 6;
  const int wr = w / WN_WAVES, wc = w % WN_WAVES;
  const int lr = ln & 15, lg = ln >> 4;

  // XCD swizzle: contiguous logical-block chunk per XCD
  const int nwg = (int)(gridDim.x * gridDim.y);
  const int lin = (int)(blockIdx.y * gridDim.x + blockIdx.x);
  const int cpx = nwg >> 3;
  const int swzb = (lin & 7) * cpx + (lin >> 3);
  const int bx = swzb % (int)gridDim.x;
  const int by = swzb / (int)gridDim.x;
  const long mBase = (long)by * BM;
  const long nBase = (long)bx * BN;

  f32x4 acc[MF][NF] = {};

  const int r0 = ln >> 2;
  const int c0 = (ln & 3) * 8;

  auto stage = [&](int buf, int k0) {
#pragma unroll
    for (int i = 0; i < BM / 64; ++i) {
      const int br = (i * 4 + w) * 16;
      GLDS16(A + (mBase + br + r0) * K + k0 + c0, lA0 + buf * BM * 32 + br * 32);
    }
#pragma unroll
    for (int i = 0; i < BN / 64; ++i) {
      const int br = (i * 4 + w) * 16;
      GLDS16(Bt + (nBase + br + r0) * K + k0 + c0, lB0 + buf * BN * 32 + br * 32);
    }
  };

  stage(0, 0);
  __syncthreads();
  int cur = 0;
  for (int k0 = 0; k0 < K; k0 += 32) {
    if (k0 + 32 < K) stage(cur ^ 1, k0 + 32);
    bf16x8 af[MF], bfv[NF];
#pragma unroll
    for (int mi = 0; mi < MF; ++mi)
      af[mi] = *(const bf16x8*)&lA0[cur * BM * 32 + (wr * WM + mi * 16 + lr) * 32 + lg * 8];
#pragma unroll
    for (int ni = 0; ni < NF; ++ni)
      bfv[ni] = *(const bf16x8*)&lB0[cur * BN * 32 + (wc * WN + ni * 16 + lr) * 32 + lg * 8];
#pragma unroll
    for (int mi = 0; mi < MF; ++mi)
#pragma unroll
      for (int ni = 0; ni < NF; ++ni)
        acc[mi][ni] = __builtin_amdgcn_mfma_f32_16x16x32_bf16(af[mi], bfv[ni],
                                                              acc[mi][ni], 0, 0, 0);
    __syncthreads();
    cur ^= 1;
  }

  if (VSPLIT && nBase >= 2048) {
    // ---- V third: write bf16(acc+bias) transposed into pool[col][row]
#pragma unroll
    for (int ni = 0; ni < NF; ++ni) {
      const int cl = wc * WN + ni * 16 + lr;
      const float bv = bias[nBase + cl];
#pragma unroll
      for (int mi = 0; mi < MF; ++mi) {
#pragma unroll
        for (int j = 0; j < 4; ++j) {
          const int rl = wr * WM + mi * 16 + lg * 4 + j;
          pool[cl * 136 + rl] = bfc(acc[mi][ni][j] + bv);
        }
      }
    }
    __syncthreads();
    // store: vout[bh][d][t], 2 threads per d-column, 64 t-values each (8x int4)
    const int c = tid >> 1, half = tid & 1;
    const long cglob = nBase + c - 2048;
    const int hh2 = (int)(cglob >> 6), d = (int)(cglob & 63);
    const int bb = (int)(mBase >> 11);
    const int t0 = (int)(mBase & 2047);
    u16* dst = vout + ((long)(bb * 16 + hh2) * 64 + d) * 2048 + t0 + half * 64;
    const u16* srcp = &pool[c * 136 + half * 64];
#pragma unroll
    for (int i = 0; i < 8; ++i)
      *(int4*)(dst + i * 8) = *(const int4*)(srcp + i * 8);
    return;
  }

#pragma unroll
  for (int ni = 0; ni < NF; ++ni) {
    const long col = nBase + wc * WN + ni * 16 + lr;
    const float bv = bias[col];
#pragma unroll
    for (int mi = 0; mi < MF; ++mi) {
      const long row = mBase + wr * WM + mi * 16 + lg * 4;
#pragma unroll
      for (int j = 0; j < 4; ++j) {
        float v = acc[mi][ni][j] + bv;
        if constexpr (sizeof(OutT) == 2) {
          C[(row + j) * N + col] = (OutT)f2bf(v);
        } else {
          C[(row + j) * N + col] = v;
        }
      }
    }
  }
}

// ------------------------------------------- flash attention v9: lag-2 pipeline
// 512 blocks x 512 thr, XCD-swizzled. 2 KV-groups x 4 q-waves; TK=32 kv tiles,
// 32 tiles/group, 4 LDS bufs/group (K 4KB + V 4KB each). Per iter t:
//   QK(t+1)[buf (t+1)%4] ; softmax(t) (overlaps QK MFMAs) ; PV(t)[buf t%4] ;
//   barrier ; stage(t+3)[buf (t+3)%4].
// Swapped-QK 32x32 MFMA, max3 tree, deferred-lsum (8 accums), permlane P-pack.
__global__ __launch_bounds__(512, 4) void attn_fwd(const u16* __restrict__ qkv,
                                                   const u16* __restrict__ vt,
                                                   u16* __restrict__ outp) {
  __shared__ __align__(16) u16 smemf[32768];  // 64 KB: [g][buf0..3][K 4K|V 4K]
  const int tid = (int)threadIdx.x;
  const int ln = tid & 63;
  const int l31 = tid & 31;
  const int hiH = (tid >> 5) & 1;
  const int w = tid >> 6;       // 0..7
  const int g = w >> 2;         // KV-half
  const int qw = w & 3;         // q-block
  const int bid0 = (int)blockIdx.x;
  const int bid = ((bid0 & 7) << 6) | (bid0 >> 3);   // XCD swizzle (512 = 8*64)
  const int qt = bid & 15;
  const int bh = bid >> 4;
  const int b = bh >> 4;
  const int hh = bh & 15;

  const float SCALE = 0.125f * 1.44269504088896f;  // 1/sqrt(64) * log2(e)
  const f32x16 fzero = {};

  // ---- Q fragments (B-operand): col=q=l31, k=d, pre-scaled
  const long qrow = (long)(b * 2048 + qt * 128 + qw * 32 + l31);
  const u16* Qp = qkv + qrow * 3072 + hh * 64;
  bf16x8 qf[4];
#pragma unroll
  for (int ks = 0; ks < 4; ++ks) {
    union { u16 u[8]; int4 i4; bf16x8 v; } in, ov;
    in.i4 = *(const int4*)(Qp + ks * 16 + hiH * 8);
#pragma unroll
    for (int e = 0; e < 8; ++e) {
      float f = __builtin_bit_cast(float, (u32)in.u[e] << 16) * SCALE;
      ov.u[e] = f2bf(f);
    }
    qf[ks] = ov.v;
  }

  f32x16 o[2] = {};
  float ls8[8] = {};
  float mrow = -1e30f;

  const u16* Kbase = qkv + ((long)b * 2048) * 3072 + 1024 + hh * 64;
  const u16* Vbase = vt + (long)bh * 64 * 2048;

  // hoisted swizzled read bases
  const char* kchar = (const char*)smemf + g * 32768 + l31 * 128;
  const char* vchar = (const char*)smemf + g * 32768 + 4096 + l31 * 64;
  const char* kptr[4];
  const char* vptr[2];
#pragma unroll
  for (int ks = 0; ks < 4; ++ks)
    kptr[ks] = kchar + ((ks * 32 + hiH * 16) ^ ((l31 & 7) << 4));
#pragma unroll
  for (int ks = 0; ks < 2; ++ks)
    vptr[ks] = vchar + ((ks * 32 + hiH * 16) ^ ((l31 & 3) << 4));

  auto stageKV = [&](int bf, int t) {
    const int kv0 = g * 1024 + t * 32;
    u16* dst = smemf + g * 16384 + bf * 4096;   // bytes: g*32768 + bf*8192
    const int rk = qw * 8 + (ln >> 3);
    const int csk = (ln & 7) ^ (rk & 7);
    GLDS16(Kbase + (long)(kv0 + rk) * 3072 + csk * 8, dst + qw * 512);
    const int rv = qw * 16 + (ln >> 2);
    const int csv = (ln & 3) ^ (rv & 3);
    GLDS16(Vbase + (long)rv * 2048 + kv0 + csv * 8, dst + 2048 + qw * 512);
  };

  auto qk = [&](int bf, f32x16& stN) {
    stN = fzero;
#pragma unroll
    for (int ks = 0; ks < 4; ++ks) {
      const bf16x8 kf = *(const bf16x8*)(kptr[ks] + bf * 8192);
      stN = __builtin_amdgcn_mfma_f32_32x32x16_bf16(kf, qf[ks], stN, 0, 0, 0);
    }
  };

  auto body = [&](int t, int bN, int bC, int bS, f32x16& stC, f32x16& stN) {
    // 1. QK(t+1) — MFMAs run in background of softmax below
    if (t + 1 < 32) qk(bN, stN);

    // 2. softmax(t): max3 tree over 16 regs + cross-half shfl
    float a0 = fmaxf(fmaxf(stC[0], stC[1]), stC[2]);
    float a1 = fmaxf(fmaxf(stC[3], stC[4]), stC[5]);
    float a2 = fmaxf(fmaxf(stC[6], stC[7]), stC[8]);
    float a3 = fmaxf(fmaxf(stC[9], stC[10]), stC[11]);
    float a4 = fmaxf(fmaxf(stC[12], stC[13]), stC[14]);
    float b0 = fmaxf(fmaxf(a0, a1), a2);
    float b1 = fmaxf(fmaxf(a3, a4), stC[15]);
    float mx = fmaxf(b0, b1);
    mx = fmaxf(mx, __shfl_xor(mx, 32));

    if (!__all(mx <= mrow + 8.0f)) {
      const float mnew = fmaxf(mrow, mx);
      const float sf = ex2(mrow - mnew);
      mrow = mnew;
#pragma unroll
      for (int r = 0; r < 8; ++r) ls8[r] *= sf;
      o[0] *= sf;
      o[1] *= sf;
    }
#pragma unroll
    for (int r = 0; r < 16; ++r) stC[r] = ex2(stC[r] - mrow);
#pragma unroll
    for (int r = 0; r < 8; ++r) ls8[r] += stC[r] + stC[r + 8];

    // 3. pack P -> pa[2] (permlane32_swap) + PV from buf bC
    bf16x8 pa[2];
#pragma unroll
    for (int gg = 0; gg < 2; ++gg) {
      const int bse = gg * 8;
      u32 A = pkbf(stC[bse + 0], stC[bse + 1]);
      u32 B = pkbf(stC[bse + 2], stC[bse + 3]);
      u32 C = pkbf(stC[bse + 4], stC[bse + 5]);
      u32 D = pkbf(stC[bse + 6], stC[bse + 7]);
      union { u32 wv[4]; bf16x8 v; } u;
#if __has_builtin(__builtin_amdgcn_permlane32_swap)
      uint2v r0 = __builtin_amdgcn_permlane32_swap(A, C, false, false);
      uint2v r1 = __builtin_amdgcn_permlane32_swap(B, D, false, false);
      u.wv[0] = r0[0]; u.wv[1] = r1[0]; u.wv[2] = r0[1]; u.wv[3] = r1[1];
#else
      const u32 sA = __shfl_xor((int)A, 32);
      const u32 sB = __shfl_xor((int)B, 32);
      const u32 sC = __shfl_xor((int)C, 32);
      const u32 sD = __shfl_xor((int)D, 32);
      u.wv[0] = hiH ? sC : A;
      u.wv[1] = hiH ? sD : B;
      u.wv[2] = hiH ? C : sA;
      u.wv[3] = hiH ? D : sB;
#endif
      pa[gg] = u.v;
    }
#pragma unroll
    for (int dt = 0; dt < 2; ++dt)
#pragma unroll
      for (int ks2 = 0; ks2 < 2; ++ks2) {
        const bf16x8 vf = *(const bf16x8*)(vptr[ks2] + bC * 8192 + dt * 2048);
        o[dt] = __builtin_amdgcn_mfma_f32_32x32x16_bf16(vf, pa[ks2], o[dt], 0, 0, 0);
      }

    // 4. barrier: all waves done reading buf bC; prior staging drained
    __syncthreads();
    // 5. prefetch tile t+3 into buf bS
    if (t + 3 < 32) stageKV(bS, t + 3);
  };

  // ---- prologue: stage 0,1,2 into bufs 0,1,2; compute QK(0)
  f32x16 stA, stB;
  stageKV(0, 0);
  __syncthreads();
  stageKV(1, 1);
  qk(0, stA);
  __syncthreads();
  stageKV(2, 2);

  for (int tb = 0; tb < 32; tb += 4) {
    body(tb + 0, 1, 0, 3, stA, stB);
    body(tb + 1, 2, 1, 0, stB, stA);
    body(tb + 2, 3, 2, 1, stA, stB);
    body(tb + 3, 0, 3, 2, stB, stA);
  }

  // ---- reduce deferred lsum, merge KV-half partials, normalize, store
  float t4[4];
#pragma unroll
  for (int r = 0; r < 4; ++r) t4[r] = ls8[r] + ls8[r + 4];
  float lsum = (t4[0] + t4[1]) + (t4[2] + t4[3]);
  const float lsum_tot = lsum + __shfl_xor(lsum, 32);

  float* PO = (float*)smemf;                       // 32 KB
  float* MLf = (float*)((char*)smemf + 32768);     // 4 KB

  if (g == 1) {
    float* dst = PO + (w - 4) * 2048 + ln * 32;
#pragma unroll
    for (int dt = 0; dt < 2; ++dt)
#pragma unroll
      for (int q4 = 0; q4 < 4; ++q4) {
        f32x4 c;
#pragma unroll
        for (int j = 0; j < 4; ++j) c[j] = o[dt][q4 * 4 + j];
        *(f32x4*)(dst + dt * 16 + q4 * 4) = c;
      }
    MLf[(w - 4) * 128 + ln * 2] = mrow;
    MLf[(w - 4) * 128 + ln * 2 + 1] = lsum_tot;
  }
  __syncthreads();
  if (g == 0) {
    const float m1v = MLf[w * 128 + ln * 2];
    const float l1 = MLf[w * 128 + ln * 2 + 1];
    const float* src = PO + w * 2048 + ln * 32;
    const float m = fmaxf(mrow, m1v);
    const float a0 = ex2(mrow - m);
    const float a1 = ex2(m1v - m);
    const float linv = 1.0f / (lsum_tot * a0 + l1 * a1);
    u16* T = (u16*)((char*)smemf + 36864) + w * (32 * 72);
#pragma unroll
    for (int dt = 0; dt < 2; ++dt) {
      float o1[16];
#pragma unroll
      for (int q4 = 0; q4 < 4; ++q4) {
        const f32x4 c = *(const f32x4*)(src + dt * 16 + q4 * 4);
#pragma unroll
        for (int j = 0; j < 4; ++j) o1[q4 * 4 + j] = c[j];
      }
#pragma unroll
      for (int r = 0; r < 16; ++r) {
        const float v = (o[dt][r] * a0 + o1[r] * a1) * linv;
        const int d = (r & 3) + 8 * (r >> 2) + 4 * hiH + dt * 32;
        T[l31 * 72 + d] = bfc(v);
      }
    }
    asm volatile("s_waitcnt lgkmcnt(0)" ::: "memory");
    __builtin_amdgcn_sched_barrier(0);
    const int rr = ln >> 1;
    const int c0 = (ln & 1) * 32;
    u16* orow = outp + ((long)(b * 2048 + qt * 128 + w * 32 + rr)) * 1024 + hh * 64 + c0;
#pragma unroll
    for (int i = 0; i < 4; ++i)
      *(int4*)(orow + i * 8) = *(const int4*)&T[rr * 72 + c0 + i * 8];
  }
}

// ----------------------------------------------------------------------------
extern "C" void kernel_launch(void* const* d_in, const int* in_sizes, int n_in,
                              void* d_out, int out_size, void* d_ws, size_t ws_size,
                              hipStream_t stream) {
  (void)in_sizes; (void)n_in; (void)out_size;
  const float* x = (const float*)d_in[0];
  const float* b_attn = (const float*)d_in[2];
  const float* b_qkv = (const float*)d_in[4];
  const float* b_proj = (const float*)d_in[6];

  char* ws = (char*)d_ws;
  const size_t MB = 1024 * 1024;
  u16* xb   = (u16*)(ws + 0 * MB);
  u16* hbuf = (u16*)(ws + 8 * MB);
  u16* qkvb = (u16*)(ws + 16 * MB);
  u16* vtb  = (u16*)(ws + 40 * MB);
  u16* aout = (u16*)(ws + 48 * MB);
  u16* wTa  = (u16*)(ws + 56 * MB);
  u16* wTq  = (u16*)(ws + 58 * MB);
  u16* wTp  = (u16*)(ws + 64 * MB);
  if (ws_size < 66 * MB) return;

  prep<<<7168, 256, 0, stream>>>(x, xb, (const float*)d_in[1], wTa,
                                 (const float*)d_in[3], wTq,
                                 (const float*)d_in[5], wTp);

  gemm_bt<64, 128, 4, u16><<<dim3(8, 64), 256, 0, stream>>>(
      xb, wTa, b_attn, hbuf, nullptr, 4096, 1024, 1024);
  // qkv GEMM: Q,K thirds -> qkvb; V third -> vtb (transposed in epilogue)
  gemm_bt<128, 128, 2, u16, true><<<dim3(24, 32), 256, 0, stream>>>(
      hbuf, wTq, b_qkv, qkvb, vtb, 4096, 3072, 1024);
  attn_fwd<<<512, 512, 0, stream>>>(qkvb, vtb, aout);
  gemm_bt<64, 128, 4, float><<<dim3(8, 64), 256, 0, stream>>>(
      aout, wTp, b_proj, (float*)d_out, nullptr, 4096, 1024, 1024);
}